// Round 8
// baseline (313.148 us; speedup 1.0000x reference)
//
#include <hip/hip_runtime.h>
#include <math.h>

#define CS 256
#define CZ 128
#define HEADS 8
#define DH 32
#define SDIM 128
#define RDIM 256
#define MROWS (SDIM*RDIM)   // 32768
#define ZROWS (RDIM*RDIM)   // 65536
#define EPSF 1e-5f
#define LOG2E 1.44269504088896340736f

typedef __attribute__((ext_vector_type(8))) short short8_t;   // 8 bf16 (4 VGPRs)
typedef __attribute__((ext_vector_type(4))) float f32x4;

__device__ __forceinline__ float waveReduceSum(float v) {
    #pragma unroll
    for (int off = 32; off > 0; off >>= 1) v += __shfl_xor(v, off, 64);
    return v;
}

__device__ __forceinline__ unsigned short f2bf(float f) {
    unsigned u = __float_as_uint(f);
    unsigned r = (u + 0x7fffu + ((u >> 16) & 1u)) >> 16;   // RNE
    return (unsigned short)r;
}

__device__ __forceinline__ float bf2f(unsigned short u) {
    return __uint_as_float(((unsigned)u) << 16);
}

// ---------------- LayerNorm of s: one wave per row of 256, bf16 out ------
__global__ __launch_bounds__(256) void ln_s_kernel(const float* __restrict__ s,
        const float* __restrict__ w, const float* __restrict__ b,
        unsigned short* __restrict__ snb) {
    int wid = threadIdx.x >> 6;
    int lane = threadIdx.x & 63;
    int row = blockIdx.x * 4 + wid;              // < 32768
    const float4 v = ((const float4*)(s + (size_t)row * CS))[lane];
    float sum = waveReduceSum(v.x + v.y + v.z + v.w);
    float sq  = waveReduceSum(v.x*v.x + v.y*v.y + v.z*v.z + v.w*v.w);
    float mean = sum * (1.f/CS);
    float var  = sq * (1.f/CS) - mean*mean;
    float rstd = rsqrtf(var + EPSF);
    const float4 wv = ((const float4*)w)[lane];
    const float4 bv = ((const float4*)b)[lane];
    ushort4 o;
    o.x = f2bf((v.x-mean)*rstd*wv.x + bv.x);
    o.y = f2bf((v.y-mean)*rstd*wv.y + bv.y);
    o.z = f2bf((v.z-mean)*rstd*wv.z + bv.z);
    o.w = f2bf((v.w-mean)*rstd*wv.w + bv.w);
    ((ushort4*)(snb + (size_t)row * CS))[lane] = o;
}

// ------- LayerNorm of z + pair bias: one wave per (q,k) row of 128 -------
// writes pb[h][q][k]
__global__ __launch_bounds__(256) void ln_z_pb_kernel(const float* __restrict__ z,
        const float* __restrict__ w, const float* __restrict__ b,
        const float* __restrict__ wz, float* __restrict__ pb) {
    int wid = threadIdx.x >> 6;
    int lane = threadIdx.x & 63;
    int row = blockIdx.x * 4 + wid;              // row = q*256 + k, < 65536
    const float2 v = ((const float2*)(z + (size_t)row * CZ))[lane];
    float sum = waveReduceSum(v.x + v.y);
    float sq  = waveReduceSum(v.x*v.x + v.y*v.y);
    float mean = sum * (1.f/CZ);
    float var  = sq * (1.f/CZ) - mean*mean;
    float rstd = rsqrtf(var + EPSF);
    const float2 wv = ((const float2*)w)[lane];
    const float2 bv = ((const float2*)b)[lane];
    float n0 = (v.x-mean)*rstd*wv.x + bv.x;
    float n1 = (v.y-mean)*rstd*wv.y + bv.y;
    const float* wz0 = wz + (size_t)(lane*2) * HEADS;   // wz: [128][8]
    float ph[8];
    #pragma unroll
    for (int h = 0; h < 8; h++) ph[h] = n0*wz0[h] + n1*wz0[HEADS + h];
    #pragma unroll
    for (int h = 0; h < 8; h++) ph[h] = waveReduceSum(ph[h]);
    if (lane == 0) {
        #pragma unroll
        for (int h = 0; h < 8; h++)
            pb[(size_t)h*ZROWS + row] = ph[h];   // [h][q][k]
    }
}

// ----- weight convert: w[k][n] fp32 -> wt[n][k] bf16 (n-major for B-frag) -
__global__ __launch_bounds__(256) void wconv_kernel(const float* __restrict__ wq,
        const float* __restrict__ wk, const float* __restrict__ wv,
        const float* __restrict__ wg, const float* __restrict__ wo,
        unsigned short* __restrict__ wtb, unsigned short* __restrict__ wot) {
    __shared__ float T[64][65];
    const int wi = blockIdx.z;
    const float* W = (wi==0)?wq:(wi==1)?wk:(wi==2)?wv:(wi==3)?wg:wo;
    unsigned short* O = (wi<4) ? (wtb + (size_t)wi*65536) : wot;
    const int bk = blockIdx.x * 64, bn = blockIdx.y * 64;
    const int tx = threadIdx.x & 63, tg = threadIdx.x >> 6;
    #pragma unroll
    for (int i = 0; i < 16; i++) {
        int r = tg*16 + i;
        T[r][tx] = W[(size_t)(bk+r)*256 + bn + tx];
    }
    __syncthreads();
    #pragma unroll
    for (int i = 0; i < 16; i++) {
        int r = tg*16 + i;
        O[(size_t)(bn+r)*256 + bk + tx] = f2bf(T[tx][r]);
    }
}

// ------------- QKVG projection GEMM (MFMA): M=32768, K=256, N=1024 -------
__global__ __launch_bounds__(256, 2) void qkvg_kernel(
        const unsigned short* __restrict__ snb,
        const unsigned short* __restrict__ wtb,
        const float* __restrict__ bg,
        unsigned short* __restrict__ qo, unsigned short* __restrict__ ko,
        unsigned short* __restrict__ vo, unsigned short* __restrict__ go) {
    __shared__ alignas(16) unsigned short As[128][72];   // pad 64->72: 2-way only
    __shared__ alignas(16) unsigned short Bs[128][72];
    const int m0 = blockIdx.x * 128;
    const int n0 = blockIdx.y * 128;             // 0..896
    const int seg = n0 >> 8;
    const int nseg = n0 & 255;                   // 0 or 128
    const unsigned short* wt = wtb + (size_t)seg * 65536;
    const int tid = threadIdx.x;
    const int lane = tid & 63, wid = tid >> 6;
    const int ln15 = lane & 15, g = lane >> 4;
    const int wr = wid >> 1, wc = wid & 1;
    f32x4 acc[4][4];
    #pragma unroll
    for (int i = 0; i < 4; i++)
        #pragma unroll
        for (int j = 0; j < 4; j++) acc[i][j] = (f32x4){0.f,0.f,0.f,0.f};

    for (int k0 = 0; k0 < 256; k0 += 64) {
        #pragma unroll
        for (int c = 0; c < 4; c++) {
            int L = tid + c*256;                 // 0..1023 chunks of 8 bf16
            int row = L >> 3, kc = (L & 7) * 8;
            *(short8_t*)&As[row][kc] =
                *(const short8_t*)&snb[(size_t)(m0+row)*256 + k0 + kc];
            *(short8_t*)&Bs[row][kc] =
                *(const short8_t*)&wt[(size_t)(nseg+row)*256 + k0 + kc];
        }
        __syncthreads();
        #pragma unroll
        for (int kk = 0; kk < 64; kk += 32) {
            short8_t a[4], b[4];
            #pragma unroll
            for (int i = 0; i < 4; i++) {
                a[i] = *(const short8_t*)&As[wr*64 + i*16 + ln15][kk + g*8];
                b[i] = *(const short8_t*)&Bs[wc*64 + i*16 + ln15][kk + g*8];
            }
            #pragma unroll
            for (int i = 0; i < 4; i++)
                #pragma unroll
                for (int j = 0; j < 4; j++)
                    acc[i][j] = __builtin_amdgcn_mfma_f32_16x16x32_bf16(
                                    a[i], b[j], acc[i][j], 0, 0, 0);
        }
        __syncthreads();
    }
    #pragma unroll
    for (int i = 0; i < 4; i++) {
        #pragma unroll
        for (int r = 0; r < 4; r++) {
            int m = m0 + wr*64 + i*16 + g*4 + r;
            int ss = m >> 8, rr = m & 255;
            #pragma unroll
            for (int j = 0; j < 4; j++) {
                int col = n0 + wc*64 + j*16 + ln15;
                int lc = col & 255;
                int h = lc >> 5, d = lc & 31;
                float val = acc[i][j][r];
                size_t qidx = (((size_t)ss*HEADS + h)*RDIM + rr)*DH + d;
                if (seg == 0)      qo[qidx] = f2bf(val * 0.17677669529663687f);
                else if (seg == 1) ko[qidx] = f2bf(val);
                else if (seg == 2) vo[qidx] = f2bf(val);
                else {
                    float x = val + bg[lc];
                    go[(size_t)m*CS + lc] = f2bf(1.f / (1.f + expf(-x)));
                }
            }
        }
    }
}

// ---- attention: swapped-QK^T MFMA flash, block per (s,h), 4 waves -------
// Wave handles 4 q-tiles of 16 rows. mfma(K,Q) -> S^T: lane owns full q-row
// (col=ln15=q) -> single-pass in-lane softmax (no online rescale).
// PV as O^T = V^T . P^T with P bounced via tiny per-wave [16][72] buffer.
__global__ __launch_bounds__(256, 3) void attn_kernel(
        const unsigned short* __restrict__ q, const unsigned short* __restrict__ k,
        const unsigned short* __restrict__ v, const float* __restrict__ pb,
        const float* __restrict__ mask, unsigned short* __restrict__ o) {
    __shared__ alignas(16) unsigned short Klds[256][40];
    __shared__ alignas(16) unsigned short Vtlds[32][264];
    __shared__ alignas(16) unsigned short Plds[4][16][72];
    __shared__ float masklds[256];

    const int sh = blockIdx.x;                   // s*8 + h
    const int ss = sh >> 3, h = sh & 7;
    const int tid = threadIdx.x;
    const int lane = tid & 63, wid = tid >> 6;
    const int ln15 = lane & 15, g = lane >> 4;   // g in 0..3

    const unsigned short* kp = k + (size_t)sh * 8192;
    const unsigned short* vp = v + (size_t)sh * 8192;
    // ---- stage K and V^T to LDS ----
    #pragma unroll
    for (int i = 0; i < 4; i++) {
        int idx = tid + i*256;                   // chunk of 8 bf16, 0..1023
        int row = idx >> 2, col = (idx & 3) * 8; // row: k-index, col: d
        short8_t kv8 = *(const short8_t*)&kp[(size_t)row*DH + col];
        short8_t vv8 = *(const short8_t*)&vp[(size_t)row*DH + col];
        *(short8_t*)&Klds[row][col] = kv8;
        #pragma unroll
        for (int e = 0; e < 8; e++)
            Vtlds[col+e][row] = (unsigned short)vv8[e];
    }
    masklds[tid] = 1e9f * (mask[(size_t)ss*RDIM + tid] - 1.f);

    // ---- Q B-frags for the wave's 4 q-tiles (col=ln15=q, k=g*8 over d) --
    short8_t qfr[4];
    {
        const unsigned short* qp = q + (size_t)sh * 8192;
        #pragma unroll
        for (int qt = 0; qt < 4; qt++)
            qfr[qt] = *(const short8_t*)&qp[(size_t)(wid*64 + qt*16 + ln15)*DH + g*8];
    }
    __syncthreads();

    const float* pbh = pb + (size_t)h * ZROWS;

    #pragma unroll 1
    for (int qt = 0; qt < 4; qt++) {
        const int q0 = wid*64 + qt*16;
        // ---- S^T = K . Q^T : one MFMA per 16-k tile, lane owns q=ln15 ---
        f32x4 st[16];
        #pragma unroll
        for (int t = 0; t < 16; t++) {
            short8_t kf = *(const short8_t*)&Klds[t*16 + ln15][g*8];
            st[t] = __builtin_amdgcn_mfma_f32_16x16x32_bf16(
                        kf, qfr[qt], (f32x4){0.f,0.f,0.f,0.f}, 0, 0, 0);
        }
        // ---- bias: pb[h][q][k] contiguous float4 + mask (bcast LDS) -----
        const float* pbrow = pbh + (size_t)(q0 + ln15)*RDIM;
        #pragma unroll
        for (int t = 0; t < 16; t++) {
            float4 pb4 = *(const float4*)(pbrow + t*16 + g*4);
            float4 mk4 = *(const float4*)&masklds[t*16 + g*4];
            st[t][0] += pb4.x + mk4.x;
            st[t][1] += pb4.y + mk4.y;
            st[t][2] += pb4.z + mk4.z;
            st[t][3] += pb4.w + mk4.w;
        }
        // ---- single-pass softmax, in-lane + 2 shuffles across g ---------
        float mx = -INFINITY;
        #pragma unroll
        for (int t = 0; t < 16; t++) {
            float a = fmaxf(fmaxf(st[t][0], st[t][1]), fmaxf(st[t][2], st[t][3]));
            mx = fmaxf(mx, a);
        }
        mx = fmaxf(mx, __shfl_xor(mx, 16, 64));
        mx = fmaxf(mx, __shfl_xor(mx, 32, 64));
        float l = 0.f;
        #pragma unroll
        for (int t = 0; t < 16; t++) {
            #pragma unroll
            for (int r = 0; r < 4; r++) {
                float p = exp2f((st[t][r] - mx) * LOG2E);
                st[t][r] = p;
                l += p;
            }
        }
        l += __shfl_xor(l, 16, 64);
        l += __shfl_xor(l, 32, 64);
        float inv = 1.f / l;
        // ---- PV per 64-k chunk: P -> Plds (b64), O^T += V^T . P^T -------
        f32x4 oacc[2];
        oacc[0] = (f32x4){0.f,0.f,0.f,0.f};
        oacc[1] = (f32x4){0.f,0.f,0.f,0.f};
        #pragma unroll
        for (int c = 0; c < 4; c++) {
            #pragma unroll
            for (int tc = 0; tc < 4; tc++) {
                int t = c*4 + tc;
                uint2 w;
                w.x = (unsigned)f2bf(st[t][0]) | ((unsigned)f2bf(st[t][1]) << 16);
                w.y = (unsigned)f2bf(st[t][2]) | ((unsigned)f2bf(st[t][3]) << 16);
                *(uint2*)&Plds[wid][ln15][tc*16 + g*4] = w;
            }
            #pragma unroll
            for (int ks = 0; ks < 2; ks++) {
                short8_t pfr = *(const short8_t*)&Plds[wid][ln15][ks*32 + g*8];
                #pragma unroll
                for (int dt = 0; dt < 2; dt++) {
                    short8_t vf = *(const short8_t*)&Vtlds[dt*16 + ln15][c*64 + ks*32 + g*8];
                    oacc[dt] = __builtin_amdgcn_mfma_f32_16x16x32_bf16(
                                   vf, pfr, oacc[dt], 0, 0, 0);
                }
            }
        }
        // ---- epilogue: O^T lane holds q=ln15, d = dt*16 + g*4 + r -------
        unsigned short* orow = o + ((size_t)ss*RDIM + q0 + ln15)*CS + h*DH;
        #pragma unroll
        for (int dt = 0; dt < 2; dt++)
            #pragma unroll
            for (int r = 0; r < 4; r++)
                orow[dt*16 + g*4 + r] = f2bf(oacc[dt][r] * inv);
    }
}

// ------------- output projection (MFMA): out = (o .* g) @ wo + bo --------
__global__ __launch_bounds__(256, 2) void outproj_kernel(
        const unsigned short* __restrict__ ob, const unsigned short* __restrict__ gb,
        const unsigned short* __restrict__ wot, const float* __restrict__ bo,
        float* __restrict__ out) {
    __shared__ alignas(16) unsigned short As[128][72];
    __shared__ alignas(16) unsigned short Bs[128][72];
    const int m0 = blockIdx.x * 128;
    const int n0 = blockIdx.y * 128;             // 0 or 128
    const int tid = threadIdx.x;
    const int lane = tid & 63, wid = tid >> 6;
    const int ln15 = lane & 15, g = lane >> 4;
    const int wr = wid >> 1, wc = wid & 1;
    f32x4 acc[4][4];
    #pragma unroll
    for (int i = 0; i < 4; i++)
        #pragma unroll
        for (int j = 0; j < 4; j++) acc[i][j] = (f32x4){0.f,0.f,0.f,0.f};

    for (int k0 = 0; k0 < 256; k0 += 64) {
        #pragma unroll
        for (int c = 0; c < 4; c++) {
            int L = tid + c*256;
            int row = L >> 3, kc = (L & 7) * 8;
            short8_t ov = *(const short8_t*)&ob[(size_t)(m0+row)*256 + k0 + kc];
            short8_t gv = *(const short8_t*)&gb[(size_t)(m0+row)*256 + k0 + kc];
            short8_t pr;
            #pragma unroll
            for (int e = 0; e < 8; e++)
                pr[e] = (short)f2bf(bf2f((unsigned short)ov[e]) *
                                    bf2f((unsigned short)gv[e]));
            *(short8_t*)&As[row][kc] = pr;
            *(short8_t*)&Bs[row][kc] =
                *(const short8_t*)&wot[(size_t)(n0+row)*256 + k0 + kc];
        }
        __syncthreads();
        #pragma unroll
        for (int kk = 0; kk < 64; kk += 32) {
            short8_t a[4], b[4];
            #pragma unroll
            for (int i = 0; i < 4; i++) {
                a[i] = *(const short8_t*)&As[wr*64 + i*16 + ln15][kk + g*8];
                b[i] = *(const short8_t*)&Bs[wc*64 + i*16 + ln15][kk + g*8];
            }
            #pragma unroll
            for (int i = 0; i < 4; i++)
                #pragma unroll
                for (int j = 0; j < 4; j++)
                    acc[i][j] = __builtin_amdgcn_mfma_f32_16x16x32_bf16(
                                    a[i], b[j], acc[i][j], 0, 0, 0);
        }
        __syncthreads();
    }
    #pragma unroll
    for (int i = 0; i < 4; i++) {
        #pragma unroll
        for (int r = 0; r < 4; r++) {
            int m = m0 + wr*64 + i*16 + g*4 + r;
            #pragma unroll
            for (int j = 0; j < 4; j++) {
                int col = n0 + wc*64 + j*16 + ln15;
                out[(size_t)m*CS + col] = acc[i][j][r] + bo[col];
            }
        }
    }
}

extern "C" void kernel_launch(void* const* d_in, const int* in_sizes, int n_in,
                              void* d_out, int out_size, void* d_ws, size_t ws_size,
                              hipStream_t stream) {
    const float* s      = (const float*)d_in[0];
    const float* z      = (const float*)d_in[1];
    const float* mask   = (const float*)d_in[2];
    const float* ln_s_w = (const float*)d_in[3];
    const float* ln_s_b = (const float*)d_in[4];
    const float* ln_z_w = (const float*)d_in[5];
    const float* ln_z_b = (const float*)d_in[6];
    const float* w_z    = (const float*)d_in[7];
    const float* w_q    = (const float*)d_in[8];
    const float* w_k    = (const float*)d_in[9];
    const float* w_v    = (const float*)d_in[10];
    const float* w_g    = (const float*)d_in[11];
    const float* b_g    = (const float*)d_in[12];
    const float* w_o    = (const float*)d_in[13];
    const float* b_o    = (const float*)d_in[14];
    float* out = (float*)d_out;
    float* ws  = (float*)d_ws;

    // Workspace layout (float units; bf16 buffers cast):
    unsigned short* snb = (unsigned short*)ws;                    // 8388608 shorts
    unsigned short* wtb = (unsigned short*)(ws + 4194304);        // 262144 shorts
    unsigned short* wot = (unsigned short*)(ws + 4194304+131072); // 65536 shorts
    float* pbv = ws + 4194304 + 131072 + 32768;                   // 524288 floats
    unsigned short* qb  = (unsigned short*)(pbv + 524288);        // 8388608 shorts each
    unsigned short* kb  = qb + 8388608;
    unsigned short* vb  = kb + 8388608;
    unsigned short* gbuf= vb + 8388608;
    unsigned short* obuf= gbuf + 8388608;
    // total = 25,853,952 floats = 103.4 MB

    ln_s_kernel<<<MROWS/4, 256, 0, stream>>>(s, ln_s_w, ln_s_b, snb);
    ln_z_pb_kernel<<<ZROWS/4, 256, 0, stream>>>(z, ln_z_w, ln_z_b, w_z, pbv);
    wconv_kernel<<<dim3(4,4,5), 256, 0, stream>>>(w_q, w_k, w_v, w_g, w_o, wtb, wot);
    qkvg_kernel<<<dim3(MROWS/128, 8), 256, 0, stream>>>(snb, wtb, b_g, qb, kb, vb, gbuf);
    attn_kernel<<<SDIM*HEADS, 256, 0, stream>>>(qb, kb, vb, pbv, mask, obuf);
    outproj_kernel<<<dim3(MROWS/128, 2), 256, 0, stream>>>(obuf, gbuf, wot, b_o, out);
}

// Round 9
// 306.225 us; speedup vs baseline: 1.0226x; 1.0226x over previous
//
#include <hip/hip_runtime.h>
#include <math.h>

#define CS 256
#define CZ 128
#define HEADS 8
#define DH 32
#define SDIM 128
#define RDIM 256
#define MROWS (SDIM*RDIM)   // 32768
#define ZROWS (RDIM*RDIM)   // 65536
#define EPSF 1e-5f
#define LOG2E 1.44269504088896340736f

typedef __attribute__((ext_vector_type(8))) short short8_t;   // 8 bf16 (4 VGPRs)
typedef __attribute__((ext_vector_type(4))) float f32x4;

__device__ __forceinline__ float waveReduceSum(float v) {
    #pragma unroll
    for (int off = 32; off > 0; off >>= 1) v += __shfl_xor(v, off, 64);
    return v;
}

__device__ __forceinline__ unsigned short f2bf(float f) {
    unsigned u = __float_as_uint(f);
    unsigned r = (u + 0x7fffu + ((u >> 16) & 1u)) >> 16;   // RNE
    return (unsigned short)r;
}

__device__ __forceinline__ float bf2f(unsigned short u) {
    return __uint_as_float(((unsigned)u) << 16);
}

// ---------------- LayerNorm of s: one wave per row of 256, bf16 out ------
__global__ __launch_bounds__(256) void ln_s_kernel(const float* __restrict__ s,
        const float* __restrict__ w, const float* __restrict__ b,
        unsigned short* __restrict__ snb) {
    int wid = threadIdx.x >> 6;
    int lane = threadIdx.x & 63;
    int row = blockIdx.x * 4 + wid;              // < 32768
    const float4 v = ((const float4*)(s + (size_t)row * CS))[lane];
    float sum = waveReduceSum(v.x + v.y + v.z + v.w);
    float sq  = waveReduceSum(v.x*v.x + v.y*v.y + v.z*v.z + v.w*v.w);
    float mean = sum * (1.f/CS);
    float var  = sq * (1.f/CS) - mean*mean;
    float rstd = rsqrtf(var + EPSF);
    const float4 wv = ((const float4*)w)[lane];
    const float4 bv = ((const float4*)b)[lane];
    ushort4 o;
    o.x = f2bf((v.x-mean)*rstd*wv.x + bv.x);
    o.y = f2bf((v.y-mean)*rstd*wv.y + bv.y);
    o.z = f2bf((v.z-mean)*rstd*wv.z + bv.z);
    o.w = f2bf((v.w-mean)*rstd*wv.w + bv.w);
    ((ushort4*)(snb + (size_t)row * CS))[lane] = o;
}

// ------- LayerNorm of z + pair bias: one wave per (q,k) row of 128 -------
// writes pb[h][q][k] as bf16
__global__ __launch_bounds__(256) void ln_z_pb_kernel(const float* __restrict__ z,
        const float* __restrict__ w, const float* __restrict__ b,
        const float* __restrict__ wz, unsigned short* __restrict__ pb) {
    int wid = threadIdx.x >> 6;
    int lane = threadIdx.x & 63;
    int row = blockIdx.x * 4 + wid;              // row = q*256 + k, < 65536
    const float2 v = ((const float2*)(z + (size_t)row * CZ))[lane];
    float sum = waveReduceSum(v.x + v.y);
    float sq  = waveReduceSum(v.x*v.x + v.y*v.y);
    float mean = sum * (1.f/CZ);
    float var  = sq * (1.f/CZ) - mean*mean;
    float rstd = rsqrtf(var + EPSF);
    const float2 wv = ((const float2*)w)[lane];
    const float2 bv = ((const float2*)b)[lane];
    float n0 = (v.x-mean)*rstd*wv.x + bv.x;
    float n1 = (v.y-mean)*rstd*wv.y + bv.y;
    const float* wz0 = wz + (size_t)(lane*2) * HEADS;   // wz: [128][8]
    float ph[8];
    #pragma unroll
    for (int h = 0; h < 8; h++) ph[h] = n0*wz0[h] + n1*wz0[HEADS + h];
    #pragma unroll
    for (int h = 0; h < 8; h++) ph[h] = waveReduceSum(ph[h]);
    if (lane == 0) {
        #pragma unroll
        for (int h = 0; h < 8; h++)
            pb[(size_t)h*ZROWS + row] = f2bf(ph[h]);   // [h][q][k] bf16
    }
}

// ----- weight convert: w[k][n] fp32 -> wt[n][k] bf16 (n-major for B-frag) -
__global__ __launch_bounds__(256) void wconv_kernel(const float* __restrict__ wq,
        const float* __restrict__ wk, const float* __restrict__ wv,
        const float* __restrict__ wg, const float* __restrict__ wo,
        unsigned short* __restrict__ wtb, unsigned short* __restrict__ wot) {
    __shared__ float T[64][65];
    const int wi = blockIdx.z;
    const float* W = (wi==0)?wq:(wi==1)?wk:(wi==2)?wv:(wi==3)?wg:wo;
    unsigned short* O = (wi<4) ? (wtb + (size_t)wi*65536) : wot;
    const int bk = blockIdx.x * 64, bn = blockIdx.y * 64;
    const int tx = threadIdx.x & 63, tg = threadIdx.x >> 6;
    #pragma unroll
    for (int i = 0; i < 16; i++) {
        int r = tg*16 + i;
        T[r][tx] = W[(size_t)(bk+r)*256 + bn + tx];
    }
    __syncthreads();
    #pragma unroll
    for (int i = 0; i < 16; i++) {
        int r = tg*16 + i;
        O[(size_t)(bn+r)*256 + bk + tx] = f2bf(T[tx][r]);
    }
}

// ------------- QKVG projection GEMM (MFMA): M=32768, K=256, N=1024 -------
__global__ __launch_bounds__(256, 2) void qkvg_kernel(
        const unsigned short* __restrict__ snb,
        const unsigned short* __restrict__ wtb,
        const float* __restrict__ bg,
        unsigned short* __restrict__ qo, unsigned short* __restrict__ ko,
        unsigned short* __restrict__ vo, unsigned short* __restrict__ go) {
    __shared__ alignas(16) unsigned short As[128][72];   // pad 64->72: 2-way only
    __shared__ alignas(16) unsigned short Bs[128][72];
    const int m0 = blockIdx.x * 128;
    const int n0 = blockIdx.y * 128;             // 0..896
    const int seg = n0 >> 8;
    const int nseg = n0 & 255;                   // 0 or 128
    const unsigned short* wt = wtb + (size_t)seg * 65536;
    const int tid = threadIdx.x;
    const int lane = tid & 63, wid = tid >> 6;
    const int ln15 = lane & 15, g = lane >> 4;
    const int wr = wid >> 1, wc = wid & 1;
    f32x4 acc[4][4];
    #pragma unroll
    for (int i = 0; i < 4; i++)
        #pragma unroll
        for (int j = 0; j < 4; j++) acc[i][j] = (f32x4){0.f,0.f,0.f,0.f};

    for (int k0 = 0; k0 < 256; k0 += 64) {
        #pragma unroll
        for (int c = 0; c < 4; c++) {
            int L = tid + c*256;                 // 0..1023 chunks of 8 bf16
            int row = L >> 3, kc = (L & 7) * 8;
            *(short8_t*)&As[row][kc] =
                *(const short8_t*)&snb[(size_t)(m0+row)*256 + k0 + kc];
            *(short8_t*)&Bs[row][kc] =
                *(const short8_t*)&wt[(size_t)(nseg+row)*256 + k0 + kc];
        }
        __syncthreads();
        #pragma unroll
        for (int kk = 0; kk < 64; kk += 32) {
            short8_t a[4], b[4];
            #pragma unroll
            for (int i = 0; i < 4; i++) {
                a[i] = *(const short8_t*)&As[wr*64 + i*16 + ln15][kk + g*8];
                b[i] = *(const short8_t*)&Bs[wc*64 + i*16 + ln15][kk + g*8];
            }
            #pragma unroll
            for (int i = 0; i < 4; i++)
                #pragma unroll
                for (int j = 0; j < 4; j++)
                    acc[i][j] = __builtin_amdgcn_mfma_f32_16x16x32_bf16(
                                    a[i], b[j], acc[i][j], 0, 0, 0);
        }
        __syncthreads();
    }
    #pragma unroll
    for (int i = 0; i < 4; i++) {
        #pragma unroll
        for (int r = 0; r < 4; r++) {
            int m = m0 + wr*64 + i*16 + g*4 + r;
            int ss = m >> 8, rr = m & 255;
            #pragma unroll
            for (int j = 0; j < 4; j++) {
                int col = n0 + wc*64 + j*16 + ln15;
                int lc = col & 255;
                int h = lc >> 5, d = lc & 31;
                float val = acc[i][j][r];
                size_t qidx = (((size_t)ss*HEADS + h)*RDIM + rr)*DH + d;
                if (seg == 0)      qo[qidx] = f2bf(val * 0.17677669529663687f);
                else if (seg == 1) ko[qidx] = f2bf(val);
                else if (seg == 2) vo[qidx] = f2bf(val);
                else {
                    float x = val + bg[lc];
                    go[(size_t)m*CS + lc] = f2bf(1.f / (1.f + expf(-x)));
                }
            }
        }
    }
}

// ---- attention: swapped-QK^T MFMA flash, block per (s,h), 4 waves -------
// Wave handles 4 q-tiles of 16 rows. mfma(K,Q) -> S^T: lane owns full q-row
// (col=ln15=q) -> single-pass in-lane softmax. pb is bf16 and PREFETCHED
// into registers above the MFMA block so vmem latency hides under QK^T.
__global__ __launch_bounds__(256, 3) void attn_kernel(
        const unsigned short* __restrict__ q, const unsigned short* __restrict__ k,
        const unsigned short* __restrict__ v, const unsigned short* __restrict__ pb,
        const float* __restrict__ mask, unsigned short* __restrict__ o) {
    __shared__ alignas(16) unsigned short Klds[256][40];
    __shared__ alignas(16) unsigned short Vtlds[32][264];
    __shared__ alignas(16) unsigned short Plds[4][16][72];
    __shared__ float masklds[256];

    const int sh = blockIdx.x;                   // s*8 + h
    const int ss = sh >> 3, h = sh & 7;
    const int tid = threadIdx.x;
    const int lane = tid & 63, wid = tid >> 6;
    const int ln15 = lane & 15, g = lane >> 4;   // g in 0..3

    const unsigned short* kp = k + (size_t)sh * 8192;
    const unsigned short* vp = v + (size_t)sh * 8192;
    // ---- stage K and V^T to LDS ----
    #pragma unroll
    for (int i = 0; i < 4; i++) {
        int idx = tid + i*256;                   // chunk of 8 bf16, 0..1023
        int row = idx >> 2, col = (idx & 3) * 8; // row: k-index, col: d
        short8_t kv8 = *(const short8_t*)&kp[(size_t)row*DH + col];
        short8_t vv8 = *(const short8_t*)&vp[(size_t)row*DH + col];
        *(short8_t*)&Klds[row][col] = kv8;
        #pragma unroll
        for (int e = 0; e < 8; e++)
            Vtlds[col+e][row] = (unsigned short)vv8[e];
    }
    masklds[tid] = 1e9f * (mask[(size_t)ss*RDIM + tid] - 1.f);

    // ---- Q B-frags for the wave's 4 q-tiles (col=ln15=q, k=g*8 over d) --
    short8_t qfr[4];
    {
        const unsigned short* qp = q + (size_t)sh * 8192;
        #pragma unroll
        for (int qt = 0; qt < 4; qt++)
            qfr[qt] = *(const short8_t*)&qp[(size_t)(wid*64 + qt*16 + ln15)*DH + g*8];
    }
    __syncthreads();

    const unsigned short* pbh = pb + (size_t)h * ZROWS;

    #pragma unroll 1
    for (int qt = 0; qt < 4; qt++) {
        const int q0 = wid*64 + qt*16;
        // ---- prefetch pb (bf16): lane needs cols t*16+g*4..+3 of row q0+ln15
        const unsigned short* pbrow = pbh + (size_t)(q0 + ln15)*RDIM;
        uint2 pbr[16];
        #pragma unroll
        for (int t = 0; t < 16; t++)
            pbr[t] = *(const uint2*)&pbrow[t*16 + g*4];
        // ---- S^T = K . Q^T : one MFMA per 16-k tile, lane owns q=ln15 ---
        f32x4 st[16];
        #pragma unroll
        for (int t = 0; t < 16; t++) {
            short8_t kf = *(const short8_t*)&Klds[t*16 + ln15][g*8];
            st[t] = __builtin_amdgcn_mfma_f32_16x16x32_bf16(
                        kf, qfr[qt], (f32x4){0.f,0.f,0.f,0.f}, 0, 0, 0);
        }
        // ---- bias: prefetched pb + mask (bcast LDS) ---------------------
        #pragma unroll
        for (int t = 0; t < 16; t++) {
            float4 mk4 = *(const float4*)&masklds[t*16 + g*4];
            st[t][0] += bf2f((unsigned short)(pbr[t].x & 0xffffu)) + mk4.x;
            st[t][1] += bf2f((unsigned short)(pbr[t].x >> 16))     + mk4.y;
            st[t][2] += bf2f((unsigned short)(pbr[t].y & 0xffffu)) + mk4.z;
            st[t][3] += bf2f((unsigned short)(pbr[t].y >> 16))     + mk4.w;
        }
        // ---- single-pass softmax, in-lane + 2 shuffles across g ---------
        float mx = -INFINITY;
        #pragma unroll
        for (int t = 0; t < 16; t++) {
            float a = fmaxf(fmaxf(st[t][0], st[t][1]), fmaxf(st[t][2], st[t][3]));
            mx = fmaxf(mx, a);
        }
        mx = fmaxf(mx, __shfl_xor(mx, 16, 64));
        mx = fmaxf(mx, __shfl_xor(mx, 32, 64));
        float l = 0.f;
        #pragma unroll
        for (int t = 0; t < 16; t++) {
            #pragma unroll
            for (int r = 0; r < 4; r++) {
                float p = exp2f((st[t][r] - mx) * LOG2E);
                st[t][r] = p;
                l += p;
            }
        }
        l += __shfl_xor(l, 16, 64);
        l += __shfl_xor(l, 32, 64);
        float inv = 1.f / l;
        // ---- PV per 64-k chunk: P -> Plds (b64), O^T += V^T . P^T -------
        f32x4 oacc[2];
        oacc[0] = (f32x4){0.f,0.f,0.f,0.f};
        oacc[1] = (f32x4){0.f,0.f,0.f,0.f};
        #pragma unroll
        for (int c = 0; c < 4; c++) {
            #pragma unroll
            for (int tc = 0; tc < 4; tc++) {
                int t = c*4 + tc;
                uint2 w;
                w.x = (unsigned)f2bf(st[t][0]) | ((unsigned)f2bf(st[t][1]) << 16);
                w.y = (unsigned)f2bf(st[t][2]) | ((unsigned)f2bf(st[t][3]) << 16);
                *(uint2*)&Plds[wid][ln15][tc*16 + g*4] = w;
            }
            #pragma unroll
            for (int ks = 0; ks < 2; ks++) {
                short8_t pfr = *(const short8_t*)&Plds[wid][ln15][ks*32 + g*8];
                #pragma unroll
                for (int dt = 0; dt < 2; dt++) {
                    short8_t vf = *(const short8_t*)&Vtlds[dt*16 + ln15][c*64 + ks*32 + g*8];
                    oacc[dt] = __builtin_amdgcn_mfma_f32_16x16x32_bf16(
                                   vf, pfr, oacc[dt], 0, 0, 0);
                }
            }
        }
        // ---- epilogue: O^T lane holds q=ln15, d = dt*16 + g*4 + r -------
        unsigned short* orow = o + ((size_t)ss*RDIM + q0 + ln15)*CS + h*DH;
        #pragma unroll
        for (int dt = 0; dt < 2; dt++)
            #pragma unroll
            for (int r = 0; r < 4; r++)
                orow[dt*16 + g*4 + r] = f2bf(oacc[dt][r] * inv);
    }
}

// ------------- output projection (MFMA): out = (o .* g) @ wo + bo --------
__global__ __launch_bounds__(256, 2) void outproj_kernel(
        const unsigned short* __restrict__ ob, const unsigned short* __restrict__ gb,
        const unsigned short* __restrict__ wot, const float* __restrict__ bo,
        float* __restrict__ out) {
    __shared__ alignas(16) unsigned short As[128][72];
    __shared__ alignas(16) unsigned short Bs[128][72];
    const int m0 = blockIdx.x * 128;
    const int n0 = blockIdx.y * 128;             // 0 or 128
    const int tid = threadIdx.x;
    const int lane = tid & 63, wid = tid >> 6;
    const int ln15 = lane & 15, g = lane >> 4;
    const int wr = wid >> 1, wc = wid & 1;
    f32x4 acc[4][4];
    #pragma unroll
    for (int i = 0; i < 4; i++)
        #pragma unroll
        for (int j = 0; j < 4; j++) acc[i][j] = (f32x4){0.f,0.f,0.f,0.f};

    for (int k0 = 0; k0 < 256; k0 += 64) {
        #pragma unroll
        for (int c = 0; c < 4; c++) {
            int L = tid + c*256;
            int row = L >> 3, kc = (L & 7) * 8;
            short8_t ov = *(const short8_t*)&ob[(size_t)(m0+row)*256 + k0 + kc];
            short8_t gv = *(const short8_t*)&gb[(size_t)(m0+row)*256 + k0 + kc];
            short8_t pr;
            #pragma unroll
            for (int e = 0; e < 8; e++)
                pr[e] = (short)f2bf(bf2f((unsigned short)ov[e]) *
                                    bf2f((unsigned short)gv[e]));
            *(short8_t*)&As[row][kc] = pr;
            *(short8_t*)&Bs[row][kc] =
                *(const short8_t*)&wot[(size_t)(n0+row)*256 + k0 + kc];
        }
        __syncthreads();
        #pragma unroll
        for (int kk = 0; kk < 64; kk += 32) {
            short8_t a[4], b[4];
            #pragma unroll
            for (int i = 0; i < 4; i++) {
                a[i] = *(const short8_t*)&As[wr*64 + i*16 + ln15][kk + g*8];
                b[i] = *(const short8_t*)&Bs[wc*64 + i*16 + ln15][kk + g*8];
            }
            #pragma unroll
            for (int i = 0; i < 4; i++)
                #pragma unroll
                for (int j = 0; j < 4; j++)
                    acc[i][j] = __builtin_amdgcn_mfma_f32_16x16x32_bf16(
                                    a[i], b[j], acc[i][j], 0, 0, 0);
        }
        __syncthreads();
    }
    #pragma unroll
    for (int i = 0; i < 4; i++) {
        #pragma unroll
        for (int r = 0; r < 4; r++) {
            int m = m0 + wr*64 + i*16 + g*4 + r;
            #pragma unroll
            for (int j = 0; j < 4; j++) {
                int col = n0 + wc*64 + j*16 + ln15;
                out[(size_t)m*CS + col] = acc[i][j][r] + bo[col];
            }
        }
    }
}

extern "C" void kernel_launch(void* const* d_in, const int* in_sizes, int n_in,
                              void* d_out, int out_size, void* d_ws, size_t ws_size,
                              hipStream_t stream) {
    const float* s      = (const float*)d_in[0];
    const float* z      = (const float*)d_in[1];
    const float* mask   = (const float*)d_in[2];
    const float* ln_s_w = (const float*)d_in[3];
    const float* ln_s_b = (const float*)d_in[4];
    const float* ln_z_w = (const float*)d_in[5];
    const float* ln_z_b = (const float*)d_in[6];
    const float* w_z    = (const float*)d_in[7];
    const float* w_q    = (const float*)d_in[8];
    const float* w_k    = (const float*)d_in[9];
    const float* w_v    = (const float*)d_in[10];
    const float* w_g    = (const float*)d_in[11];
    const float* b_g    = (const float*)d_in[12];
    const float* w_o    = (const float*)d_in[13];
    const float* b_o    = (const float*)d_in[14];
    float* out = (float*)d_out;
    float* ws  = (float*)d_ws;

    // Workspace layout (float units; bf16 buffers cast):
    unsigned short* snb = (unsigned short*)ws;                    // 8388608 shorts
    unsigned short* wtb = (unsigned short*)(ws + 4194304);        // 262144 shorts
    unsigned short* wot = (unsigned short*)(ws + 4194304+131072); // 65536 shorts
    unsigned short* pbb = (unsigned short*)(ws + 4194304+131072+32768); // 524288 shorts (bf16)
    float* after_pb = ws + 4194304 + 131072 + 32768 + 262144;
    unsigned short* qb  = (unsigned short*)after_pb;              // 8388608 shorts each
    unsigned short* kb  = qb + 8388608;
    unsigned short* vb  = kb + 8388608;
    unsigned short* gbuf= vb + 8388608;
    unsigned short* obuf= gbuf + 8388608;

    ln_s_kernel<<<MROWS/4, 256, 0, stream>>>(s, ln_s_w, ln_s_b, snb);
    ln_z_pb_kernel<<<ZROWS/4, 256, 0, stream>>>(z, ln_z_w, ln_z_b, w_z, pbb);
    wconv_kernel<<<dim3(4,4,5), 256, 0, stream>>>(w_q, w_k, w_v, w_g, w_o, wtb, wot);
    qkvg_kernel<<<dim3(MROWS/128, 8), 256, 0, stream>>>(snb, wtb, b_g, qb, kb, vb, gbuf);
    attn_kernel<<<SDIM*HEADS, 256, 0, stream>>>(qb, kb, vb, pbb, mask, obuf);
    outproj_kernel<<<dim3(MROWS/128, 2), 256, 0, stream>>>(obuf, gbuf, wot, b_o, out);
}

// Round 10
// 241.035 us; speedup vs baseline: 1.2992x; 1.2705x over previous
//
#include <hip/hip_runtime.h>
#include <math.h>

#define CS 256
#define CZ 128
#define HEADS 8
#define DH 32
#define SDIM 128
#define RDIM 256
#define MROWS (SDIM*RDIM)   // 32768
#define ZROWS (RDIM*RDIM)   // 65536
#define EPSF 1e-5f
#define LOG2E 1.44269504088896340736f

typedef __attribute__((ext_vector_type(8))) short short8_t;   // 8 bf16 (4 VGPRs)
typedef __attribute__((ext_vector_type(4))) float f32x4;

__device__ __forceinline__ float waveReduceSum(float v) {
    #pragma unroll
    for (int off = 32; off > 0; off >>= 1) v += __shfl_xor(v, off, 64);
    return v;
}

__device__ __forceinline__ unsigned short f2bf(float f) {
    unsigned u = __float_as_uint(f);
    unsigned r = (u + 0x7fffu + ((u >> 16) & 1u)) >> 16;   // RNE
    return (unsigned short)r;
}

__device__ __forceinline__ float bf2f(unsigned short u) {
    return __uint_as_float(((unsigned)u) << 16);
}

// ---------------- LayerNorm of s: one wave per row of 256, bf16 out ------
__global__ __launch_bounds__(256) void ln_s_kernel(const float* __restrict__ s,
        const float* __restrict__ w, const float* __restrict__ b,
        unsigned short* __restrict__ snb) {
    int wid = threadIdx.x >> 6;
    int lane = threadIdx.x & 63;
    int row = blockIdx.x * 4 + wid;              // < 32768
    const float4 v = ((const float4*)(s + (size_t)row * CS))[lane];
    float sum = waveReduceSum(v.x + v.y + v.z + v.w);
    float sq  = waveReduceSum(v.x*v.x + v.y*v.y + v.z*v.z + v.w*v.w);
    float mean = sum * (1.f/CS);
    float var  = sq * (1.f/CS) - mean*mean;
    float rstd = rsqrtf(var + EPSF);
    const float4 wv = ((const float4*)w)[lane];
    const float4 bv = ((const float4*)b)[lane];
    ushort4 o;
    o.x = f2bf((v.x-mean)*rstd*wv.x + bv.x);
    o.y = f2bf((v.y-mean)*rstd*wv.y + bv.y);
    o.z = f2bf((v.z-mean)*rstd*wv.z + bv.z);
    o.w = f2bf((v.w-mean)*rstd*wv.w + bv.w);
    ((ushort4*)(snb + (size_t)row * CS))[lane] = o;
}

// ------- LayerNorm of z + pair bias: one wave per (q,k) row of 128 -------
// writes pb[h][q][k] as bf16
__global__ __launch_bounds__(256) void ln_z_pb_kernel(const float* __restrict__ z,
        const float* __restrict__ w, const float* __restrict__ b,
        const float* __restrict__ wz, unsigned short* __restrict__ pb) {
    int wid = threadIdx.x >> 6;
    int lane = threadIdx.x & 63;
    int row = blockIdx.x * 4 + wid;              // row = q*256 + k, < 65536
    const float2 v = ((const float2*)(z + (size_t)row * CZ))[lane];
    float sum = waveReduceSum(v.x + v.y);
    float sq  = waveReduceSum(v.x*v.x + v.y*v.y);
    float mean = sum * (1.f/CZ);
    float var  = sq * (1.f/CZ) - mean*mean;
    float rstd = rsqrtf(var + EPSF);
    const float2 wv = ((const float2*)w)[lane];
    const float2 bv = ((const float2*)b)[lane];
    float n0 = (v.x-mean)*rstd*wv.x + bv.x;
    float n1 = (v.y-mean)*rstd*wv.y + bv.y;
    const float* wz0 = wz + (size_t)(lane*2) * HEADS;   // wz: [128][8]
    float ph[8];
    #pragma unroll
    for (int h = 0; h < 8; h++) ph[h] = n0*wz0[h] + n1*wz0[HEADS + h];
    #pragma unroll
    for (int h = 0; h < 8; h++) ph[h] = waveReduceSum(ph[h]);
    if (lane == 0) {
        #pragma unroll
        for (int h = 0; h < 8; h++)
            pb[(size_t)h*ZROWS + row] = f2bf(ph[h]);   // [h][q][k] bf16
    }
}

// ----- weight convert: w[k][n] fp32 -> wt[n][k] bf16 (n-major for B-frag) -
__global__ __launch_bounds__(256) void wconv_kernel(const float* __restrict__ wq,
        const float* __restrict__ wk, const float* __restrict__ wv,
        const float* __restrict__ wg, const float* __restrict__ wo,
        unsigned short* __restrict__ wtb, unsigned short* __restrict__ wot) {
    __shared__ float T[64][65];
    const int wi = blockIdx.z;
    const float* W = (wi==0)?wq:(wi==1)?wk:(wi==2)?wv:(wi==3)?wg:wo;
    unsigned short* O = (wi<4) ? (wtb + (size_t)wi*65536) : wot;
    const int bk = blockIdx.x * 64, bn = blockIdx.y * 64;
    const int tx = threadIdx.x & 63, tg = threadIdx.x >> 6;
    #pragma unroll
    for (int i = 0; i < 16; i++) {
        int r = tg*16 + i;
        T[r][tx] = W[(size_t)(bk+r)*256 + bn + tx];
    }
    __syncthreads();
    #pragma unroll
    for (int i = 0; i < 16; i++) {
        int r = tg*16 + i;
        O[(size_t)(bn+r)*256 + bk + tx] = f2bf(T[tx][r]);
    }
}

// ------------- QKVG projection GEMM (MFMA): M=32768, K=256, N=1024 -------
__global__ __launch_bounds__(256, 2) void qkvg_kernel(
        const unsigned short* __restrict__ snb,
        const unsigned short* __restrict__ wtb,
        const float* __restrict__ bg,
        unsigned short* __restrict__ qo, unsigned short* __restrict__ ko,
        unsigned short* __restrict__ vo, unsigned short* __restrict__ go) {
    __shared__ alignas(16) unsigned short As[128][72];   // pad 64->72: 2-way only
    __shared__ alignas(16) unsigned short Bs[128][72];
    const int m0 = blockIdx.x * 128;
    const int n0 = blockIdx.y * 128;             // 0..896
    const int seg = n0 >> 8;
    const int nseg = n0 & 255;                   // 0 or 128
    const unsigned short* wt = wtb + (size_t)seg * 65536;
    const int tid = threadIdx.x;
    const int lane = tid & 63, wid = tid >> 6;
    const int ln15 = lane & 15, g = lane >> 4;
    const int wr = wid >> 1, wc = wid & 1;
    f32x4 acc[4][4];
    #pragma unroll
    for (int i = 0; i < 4; i++)
        #pragma unroll
        for (int j = 0; j < 4; j++) acc[i][j] = (f32x4){0.f,0.f,0.f,0.f};

    for (int k0 = 0; k0 < 256; k0 += 64) {
        #pragma unroll
        for (int c = 0; c < 4; c++) {
            int L = tid + c*256;                 // 0..1023 chunks of 8 bf16
            int row = L >> 3, kc = (L & 7) * 8;
            *(short8_t*)&As[row][kc] =
                *(const short8_t*)&snb[(size_t)(m0+row)*256 + k0 + kc];
            *(short8_t*)&Bs[row][kc] =
                *(const short8_t*)&wt[(size_t)(nseg+row)*256 + k0 + kc];
        }
        __syncthreads();
        #pragma unroll
        for (int kk = 0; kk < 64; kk += 32) {
            short8_t a[4], b[4];
            #pragma unroll
            for (int i = 0; i < 4; i++) {
                a[i] = *(const short8_t*)&As[wr*64 + i*16 + ln15][kk + g*8];
                b[i] = *(const short8_t*)&Bs[wc*64 + i*16 + ln15][kk + g*8];
            }
            #pragma unroll
            for (int i = 0; i < 4; i++)
                #pragma unroll
                for (int j = 0; j < 4; j++)
                    acc[i][j] = __builtin_amdgcn_mfma_f32_16x16x32_bf16(
                                    a[i], b[j], acc[i][j], 0, 0, 0);
        }
        __syncthreads();
    }
    #pragma unroll
    for (int i = 0; i < 4; i++) {
        #pragma unroll
        for (int r = 0; r < 4; r++) {
            int m = m0 + wr*64 + i*16 + g*4 + r;
            int ss = m >> 8, rr = m & 255;
            #pragma unroll
            for (int j = 0; j < 4; j++) {
                int col = n0 + wc*64 + j*16 + ln15;
                int lc = col & 255;
                int h = lc >> 5, d = lc & 31;
                float val = acc[i][j][r];
                size_t qidx = (((size_t)ss*HEADS + h)*RDIM + rr)*DH + d;
                if (seg == 0)      qo[qidx] = f2bf(val * 0.17677669529663687f);
                else if (seg == 1) ko[qidx] = f2bf(val);
                else if (seg == 2) vo[qidx] = f2bf(val);
                else {
                    float x = val + bg[lc];
                    go[(size_t)m*CS + lc] = f2bf(1.f / (1.f + expf(-x)));
                }
            }
        }
    }
}

// ---- attention: swapped-QK^T MFMA flash, block per (s,h), 4 waves -------
// Wave handles 4 q-tiles of 16 rows. mfma(K,Q) -> S^T: lane owns full q-row.
// pb staged per-wave into LDS with full-line (64B/row) global reads issued
// BEFORE the QK^T MFMAs; O written back via LDS transpose bounce so each
// global store is a full 64B line. PBlds triple-duty: pb tile / P / O bounce.
__global__ __launch_bounds__(256, 2) void attn_kernel(
        const unsigned short* __restrict__ q, const unsigned short* __restrict__ k,
        const unsigned short* __restrict__ v, const unsigned short* __restrict__ pb,
        const float* __restrict__ mask, unsigned short* __restrict__ o) {
    __shared__ alignas(16) unsigned short Klds[256][40];
    __shared__ alignas(16) unsigned short Vtlds[32][264];
    __shared__ alignas(16) unsigned short PBlds[4][16][264];
    __shared__ float masklds[256];

    const int sh = blockIdx.x;                   // s*8 + h
    const int ss = sh >> 3, h = sh & 7;
    const int tid = threadIdx.x;
    const int lane = tid & 63, wid = tid >> 6;
    const int ln15 = lane & 15, g = lane >> 4;   // g in 0..3

    const unsigned short* kp = k + (size_t)sh * 8192;
    const unsigned short* vp = v + (size_t)sh * 8192;
    // ---- stage K and V^T to LDS ----
    #pragma unroll
    for (int i = 0; i < 4; i++) {
        int idx = tid + i*256;                   // chunk of 8 bf16, 0..1023
        int row = idx >> 2, col = (idx & 3) * 8; // row: k-index, col: d
        short8_t kv8 = *(const short8_t*)&kp[(size_t)row*DH + col];
        short8_t vv8 = *(const short8_t*)&vp[(size_t)row*DH + col];
        *(short8_t*)&Klds[row][col] = kv8;
        #pragma unroll
        for (int e = 0; e < 8; e++)
            Vtlds[col+e][row] = (unsigned short)vv8[e];
    }
    masklds[tid] = 1e9f * (mask[(size_t)ss*RDIM + tid] - 1.f);

    // ---- Q B-frags for the wave's 4 q-tiles (col=ln15=q, k=g*8 over d) --
    short8_t qfr[4];
    {
        const unsigned short* qp = q + (size_t)sh * 8192;
        #pragma unroll
        for (int qt = 0; qt < 4; qt++)
            qfr[qt] = *(const short8_t*)&qp[(size_t)(wid*64 + qt*16 + ln15)*DH + g*8];
    }
    __syncthreads();

    const unsigned short* pbh = pb + (size_t)h * ZROWS;

    #pragma unroll 1
    for (int qt = 0; qt < 4; qt++) {
        const int q0 = wid*64 + qt*16;
        // ---- issue pb tile loads (full 64B lines: 4 lanes x 16B per row) -
        const unsigned short* pbrow = pbh + (size_t)(q0 + ln15)*RDIM;
        uint4 pbld[8];
        #pragma unroll
        for (int j = 0; j < 8; j++)
            pbld[j] = *(const uint4*)&pbrow[j*32 + g*8];
        // ---- S^T = K . Q^T (LDS-only deps; pb loads in flight) ----------
        f32x4 st[16];
        #pragma unroll
        for (int t = 0; t < 16; t++) {
            short8_t kf = *(const short8_t*)&Klds[t*16 + ln15][g*8];
            st[t] = __builtin_amdgcn_mfma_f32_16x16x32_bf16(
                        kf, qfr[qt], (f32x4){0.f,0.f,0.f,0.f}, 0, 0, 0);
        }
        // ---- land pb into per-wave LDS tile -----------------------------
        #pragma unroll
        for (int j = 0; j < 8; j++)
            *(uint4*)&PBlds[wid][ln15][j*32 + g*8] = pbld[j];
        // ---- bias: pb (LDS) + mask (bcast LDS) --------------------------
        #pragma unroll
        for (int t = 0; t < 16; t++) {
            uint2 p2 = *(const uint2*)&PBlds[wid][ln15][t*16 + g*4];
            float4 mk4 = *(const float4*)&masklds[t*16 + g*4];
            st[t][0] += bf2f((unsigned short)(p2.x & 0xffffu)) + mk4.x;
            st[t][1] += bf2f((unsigned short)(p2.x >> 16))     + mk4.y;
            st[t][2] += bf2f((unsigned short)(p2.y & 0xffffu)) + mk4.z;
            st[t][3] += bf2f((unsigned short)(p2.y >> 16))     + mk4.w;
        }
        // ---- single-pass softmax, in-lane + 2 shuffles across g ---------
        float mx = -INFINITY;
        #pragma unroll
        for (int t = 0; t < 16; t++) {
            float a = fmaxf(fmaxf(st[t][0], st[t][1]), fmaxf(st[t][2], st[t][3]));
            mx = fmaxf(mx, a);
        }
        mx = fmaxf(mx, __shfl_xor(mx, 16, 64));
        mx = fmaxf(mx, __shfl_xor(mx, 32, 64));
        float l = 0.f;
        #pragma unroll
        for (int t = 0; t < 16; t++) {
            #pragma unroll
            for (int r = 0; r < 4; r++) {
                float p = exp2f((st[t][r] - mx) * LOG2E);
                st[t][r] = p;
                l += p;
            }
        }
        l += __shfl_xor(l, 16, 64);
        l += __shfl_xor(l, 32, 64);
        float inv = 1.f / l;
        // ---- PV per 64-k chunk: P -> PBlds (b64), O^T += V^T . P^T ------
        f32x4 oacc[2];
        oacc[0] = (f32x4){0.f,0.f,0.f,0.f};
        oacc[1] = (f32x4){0.f,0.f,0.f,0.f};
        #pragma unroll
        for (int c = 0; c < 4; c++) {
            #pragma unroll
            for (int tc = 0; tc < 4; tc++) {
                int t = c*4 + tc;
                uint2 w;
                w.x = (unsigned)f2bf(st[t][0]) | ((unsigned)f2bf(st[t][1]) << 16);
                w.y = (unsigned)f2bf(st[t][2]) | ((unsigned)f2bf(st[t][3]) << 16);
                *(uint2*)&PBlds[wid][ln15][tc*16 + g*4] = w;
            }
            #pragma unroll
            for (int ks = 0; ks < 2; ks++) {
                short8_t pfr = *(const short8_t*)&PBlds[wid][ln15][ks*32 + g*8];
                #pragma unroll
                for (int dt = 0; dt < 2; dt++) {
                    short8_t vf = *(const short8_t*)&Vtlds[dt*16 + ln15][c*64 + ks*32 + g*8];
                    oacc[dt] = __builtin_amdgcn_mfma_f32_16x16x32_bf16(
                                   vf, pfr, oacc[dt], 0, 0, 0);
                }
            }
        }
        // ---- epilogue: O^T -> PBlds [q][d] -> coalesced 16B stores ------
        #pragma unroll
        for (int dt = 0; dt < 2; dt++) {
            uint2 w;
            w.x = (unsigned)f2bf(oacc[dt][0]*inv) | ((unsigned)f2bf(oacc[dt][1]*inv) << 16);
            w.y = (unsigned)f2bf(oacc[dt][2]*inv) | ((unsigned)f2bf(oacc[dt][3]*inv) << 16);
            *(uint2*)&PBlds[wid][ln15][dt*16 + g*4] = w;
        }
        {
            int qr = lane >> 2, dc = (lane & 3) * 8;
            short8_t ov = *(const short8_t*)&PBlds[wid][qr][dc];
            *(short8_t*)&o[((size_t)ss*RDIM + q0 + qr)*CS + h*DH + dc] = ov;
        }
    }
}

// ------------- output projection (MFMA): out = (o .* g) @ wo + bo --------
__global__ __launch_bounds__(256, 2) void outproj_kernel(
        const unsigned short* __restrict__ ob, const unsigned short* __restrict__ gb,
        const unsigned short* __restrict__ wot, const float* __restrict__ bo,
        float* __restrict__ out) {
    __shared__ alignas(16) unsigned short As[128][72];
    __shared__ alignas(16) unsigned short Bs[128][72];
    const int m0 = blockIdx.x * 128;
    const int n0 = blockIdx.y * 128;             // 0 or 128
    const int tid = threadIdx.x;
    const int lane = tid & 63, wid = tid >> 6;
    const int ln15 = lane & 15, g = lane >> 4;
    const int wr = wid >> 1, wc = wid & 1;
    f32x4 acc[4][4];
    #pragma unroll
    for (int i = 0; i < 4; i++)
        #pragma unroll
        for (int j = 0; j < 4; j++) acc[i][j] = (f32x4){0.f,0.f,0.f,0.f};

    for (int k0 = 0; k0 < 256; k0 += 64) {
        #pragma unroll
        for (int c = 0; c < 4; c++) {
            int L = tid + c*256;
            int row = L >> 3, kc = (L & 7) * 8;
            short8_t ov = *(const short8_t*)&ob[(size_t)(m0+row)*256 + k0 + kc];
            short8_t gv = *(const short8_t*)&gb[(size_t)(m0+row)*256 + k0 + kc];
            short8_t pr;
            #pragma unroll
            for (int e = 0; e < 8; e++)
                pr[e] = (short)f2bf(bf2f((unsigned short)ov[e]) *
                                    bf2f((unsigned short)gv[e]));
            *(short8_t*)&As[row][kc] = pr;
            *(short8_t*)&Bs[row][kc] =
                *(const short8_t*)&wot[(size_t)(n0+row)*256 + k0 + kc];
        }
        __syncthreads();
        #pragma unroll
        for (int kk = 0; kk < 64; kk += 32) {
            short8_t a[4], b[4];
            #pragma unroll
            for (int i = 0; i < 4; i++) {
                a[i] = *(const short8_t*)&As[wr*64 + i*16 + ln15][kk + g*8];
                b[i] = *(const short8_t*)&Bs[wc*64 + i*16 + ln15][kk + g*8];
            }
            #pragma unroll
            for (int i = 0; i < 4; i++)
                #pragma unroll
                for (int j = 0; j < 4; j++)
                    acc[i][j] = __builtin_amdgcn_mfma_f32_16x16x32_bf16(
                                    a[i], b[j], acc[i][j], 0, 0, 0);
        }
        __syncthreads();
    }
    #pragma unroll
    for (int i = 0; i < 4; i++) {
        #pragma unroll
        for (int r = 0; r < 4; r++) {
            int m = m0 + wr*64 + i*16 + g*4 + r;
            #pragma unroll
            for (int j = 0; j < 4; j++) {
                int col = n0 + wc*64 + j*16 + ln15;
                out[(size_t)m*CS + col] = acc[i][j][r] + bo[col];
            }
        }
    }
}

extern "C" void kernel_launch(void* const* d_in, const int* in_sizes, int n_in,
                              void* d_out, int out_size, void* d_ws, size_t ws_size,
                              hipStream_t stream) {
    const float* s      = (const float*)d_in[0];
    const float* z      = (const float*)d_in[1];
    const float* mask   = (const float*)d_in[2];
    const float* ln_s_w = (const float*)d_in[3];
    const float* ln_s_b = (const float*)d_in[4];
    const float* ln_z_w = (const float*)d_in[5];
    const float* ln_z_b = (const float*)d_in[6];
    const float* w_z    = (const float*)d_in[7];
    const float* w_q    = (const float*)d_in[8];
    const float* w_k    = (const float*)d_in[9];
    const float* w_v    = (const float*)d_in[10];
    const float* w_g    = (const float*)d_in[11];
    const float* b_g    = (const float*)d_in[12];
    const float* w_o    = (const float*)d_in[13];
    const float* b_o    = (const float*)d_in[14];
    float* out = (float*)d_out;
    float* ws  = (float*)d_ws;

    // Workspace layout (float units; bf16 buffers cast):
    unsigned short* snb = (unsigned short*)ws;                    // 8388608 shorts
    unsigned short* wtb = (unsigned short*)(ws + 4194304);        // 262144 shorts
    unsigned short* wot = (unsigned short*)(ws + 4194304+131072); // 65536 shorts
    unsigned short* pbb = (unsigned short*)(ws + 4194304+131072+32768); // 524288 shorts (bf16)
    float* after_pb = ws + 4194304 + 131072 + 32768 + 262144;
    unsigned short* qb  = (unsigned short*)after_pb;              // 8388608 shorts each
    unsigned short* kb  = qb + 8388608;
    unsigned short* vb  = kb + 8388608;
    unsigned short* gbuf= vb + 8388608;
    unsigned short* obuf= gbuf + 8388608;

    ln_s_kernel<<<MROWS/4, 256, 0, stream>>>(s, ln_s_w, ln_s_b, snb);
    ln_z_pb_kernel<<<ZROWS/4, 256, 0, stream>>>(z, ln_z_w, ln_z_b, w_z, pbb);
    wconv_kernel<<<dim3(4,4,5), 256, 0, stream>>>(w_q, w_k, w_v, w_g, w_o, wtb, wot);
    qkvg_kernel<<<dim3(MROWS/128, 8), 256, 0, stream>>>(snb, wtb, b_g, qb, kb, vb, gbuf);
    attn_kernel<<<SDIM*HEADS, 256, 0, stream>>>(qb, kb, vb, pbb, mask, obuf);
    outproj_kernel<<<dim3(MROWS/128, 2), 256, 0, stream>>>(obuf, gbuf, wot, b_o, out);
}

// Round 11
// 207.690 us; speedup vs baseline: 1.5078x; 1.1606x over previous
//
#include <hip/hip_runtime.h>
#include <math.h>

#define CS 256
#define CZ 128
#define HEADS 8
#define DH 32
#define SDIM 128
#define RDIM 256
#define MROWS (SDIM*RDIM)   // 32768
#define ZROWS (RDIM*RDIM)   // 65536
#define EPSF 1e-5f
#define LOG2E 1.44269504088896340736f

typedef __attribute__((ext_vector_type(8))) short short8_t;   // 8 bf16 (4 VGPRs)
typedef __attribute__((ext_vector_type(4))) float f32x4;

__device__ __forceinline__ float waveReduceSum(float v) {
    #pragma unroll
    for (int off = 32; off > 0; off >>= 1) v += __shfl_xor(v, off, 64);
    return v;
}

__device__ __forceinline__ unsigned short f2bf(float f) {
    unsigned u = __float_as_uint(f);
    unsigned r = (u + 0x7fffu + ((u >> 16) & 1u)) >> 16;   // RNE
    return (unsigned short)r;
}

__device__ __forceinline__ float bf2f(unsigned short u) {
    return __uint_as_float(((unsigned)u) << 16);
}

// ---------------- LayerNorm of s: one wave per row of 256, bf16 out ------
__global__ __launch_bounds__(256) void ln_s_kernel(const float* __restrict__ s,
        const float* __restrict__ w, const float* __restrict__ b,
        unsigned short* __restrict__ snb) {
    int wid = threadIdx.x >> 6;
    int lane = threadIdx.x & 63;
    int row = blockIdx.x * 4 + wid;              // < 32768
    const float4 v = ((const float4*)(s + (size_t)row * CS))[lane];
    float sum = waveReduceSum(v.x + v.y + v.z + v.w);
    float sq  = waveReduceSum(v.x*v.x + v.y*v.y + v.z*v.z + v.w*v.w);
    float mean = sum * (1.f/CS);
    float var  = sq * (1.f/CS) - mean*mean;
    float rstd = rsqrtf(var + EPSF);
    const float4 wv = ((const float4*)w)[lane];
    const float4 bv = ((const float4*)b)[lane];
    ushort4 o;
    o.x = f2bf((v.x-mean)*rstd*wv.x + bv.x);
    o.y = f2bf((v.y-mean)*rstd*wv.y + bv.y);
    o.z = f2bf((v.z-mean)*rstd*wv.z + bv.z);
    o.w = f2bf((v.w-mean)*rstd*wv.w + bv.w);
    ((ushort4*)(snb + (size_t)row * CS))[lane] = o;
}

// ------- LayerNorm of z + pair bias: one wave per (q,k) row of 128 -------
// writes pb[h][q][k] as bf16
__global__ __launch_bounds__(256) void ln_z_pb_kernel(const float* __restrict__ z,
        const float* __restrict__ w, const float* __restrict__ b,
        const float* __restrict__ wz, unsigned short* __restrict__ pb) {
    int wid = threadIdx.x >> 6;
    int lane = threadIdx.x & 63;
    int row = blockIdx.x * 4 + wid;              // row = q*256 + k, < 65536
    const float2 v = ((const float2*)(z + (size_t)row * CZ))[lane];
    float sum = waveReduceSum(v.x + v.y);
    float sq  = waveReduceSum(v.x*v.x + v.y*v.y);
    float mean = sum * (1.f/CZ);
    float var  = sq * (1.f/CZ) - mean*mean;
    float rstd = rsqrtf(var + EPSF);
    const float2 wv = ((const float2*)w)[lane];
    const float2 bv = ((const float2*)b)[lane];
    float n0 = (v.x-mean)*rstd*wv.x + bv.x;
    float n1 = (v.y-mean)*rstd*wv.y + bv.y;
    const float* wz0 = wz + (size_t)(lane*2) * HEADS;   // wz: [128][8]
    float ph[8];
    #pragma unroll
    for (int h = 0; h < 8; h++) ph[h] = n0*wz0[h] + n1*wz0[HEADS + h];
    #pragma unroll
    for (int h = 0; h < 8; h++) ph[h] = waveReduceSum(ph[h]);
    if (lane == 0) {
        #pragma unroll
        for (int h = 0; h < 8; h++)
            pb[(size_t)h*ZROWS + row] = f2bf(ph[h]);   // [h][q][k] bf16
    }
}

// ----- weight convert: w[k][n] fp32 -> wt[n][k] bf16 (n-major for B-frag) -
__global__ __launch_bounds__(256) void wconv_kernel(const float* __restrict__ wq,
        const float* __restrict__ wk, const float* __restrict__ wv,
        const float* __restrict__ wg, const float* __restrict__ wo,
        unsigned short* __restrict__ wtb, unsigned short* __restrict__ wot) {
    __shared__ float T[64][65];
    const int wi = blockIdx.z;
    const float* W = (wi==0)?wq:(wi==1)?wk:(wi==2)?wv:(wi==3)?wg:wo;
    unsigned short* O = (wi<4) ? (wtb + (size_t)wi*65536) : wot;
    const int bk = blockIdx.x * 64, bn = blockIdx.y * 64;
    const int tx = threadIdx.x & 63, tg = threadIdx.x >> 6;
    #pragma unroll
    for (int i = 0; i < 16; i++) {
        int r = tg*16 + i;
        T[r][tx] = W[(size_t)(bk+r)*256 + bn + tx];
    }
    __syncthreads();
    #pragma unroll
    for (int i = 0; i < 16; i++) {
        int r = tg*16 + i;
        O[(size_t)(bn+r)*256 + bk + tx] = f2bf(T[tx][r]);
    }
}

// ------------- QKVG projection GEMM (MFMA): M=32768, K=256, N=1024 -------
__global__ __launch_bounds__(256, 2) void qkvg_kernel(
        const unsigned short* __restrict__ snb,
        const unsigned short* __restrict__ wtb,
        const float* __restrict__ bg,
        unsigned short* __restrict__ qo, unsigned short* __restrict__ ko,
        unsigned short* __restrict__ vo, unsigned short* __restrict__ go) {
    __shared__ alignas(16) unsigned short As[128][72];   // pad 64->72: 2-way only
    __shared__ alignas(16) unsigned short Bs[128][72];
    const int m0 = blockIdx.x * 128;
    const int n0 = blockIdx.y * 128;             // 0..896
    const int seg = n0 >> 8;
    const int nseg = n0 & 255;                   // 0 or 128
    const unsigned short* wt = wtb + (size_t)seg * 65536;
    const int tid = threadIdx.x;
    const int lane = tid & 63, wid = tid >> 6;
    const int ln15 = lane & 15, g = lane >> 4;
    const int wr = wid >> 1, wc = wid & 1;
    f32x4 acc[4][4];
    #pragma unroll
    for (int i = 0; i < 4; i++)
        #pragma unroll
        for (int j = 0; j < 4; j++) acc[i][j] = (f32x4){0.f,0.f,0.f,0.f};

    for (int k0 = 0; k0 < 256; k0 += 64) {
        #pragma unroll
        for (int c = 0; c < 4; c++) {
            int L = tid + c*256;                 // 0..1023 chunks of 8 bf16
            int row = L >> 3, kc = (L & 7) * 8;
            *(short8_t*)&As[row][kc] =
                *(const short8_t*)&snb[(size_t)(m0+row)*256 + k0 + kc];
            *(short8_t*)&Bs[row][kc] =
                *(const short8_t*)&wt[(size_t)(nseg+row)*256 + k0 + kc];
        }
        __syncthreads();
        #pragma unroll
        for (int kk = 0; kk < 64; kk += 32) {
            short8_t a[4], b[4];
            #pragma unroll
            for (int i = 0; i < 4; i++) {
                a[i] = *(const short8_t*)&As[wr*64 + i*16 + ln15][kk + g*8];
                b[i] = *(const short8_t*)&Bs[wc*64 + i*16 + ln15][kk + g*8];
            }
            #pragma unroll
            for (int i = 0; i < 4; i++)
                #pragma unroll
                for (int j = 0; j < 4; j++)
                    acc[i][j] = __builtin_amdgcn_mfma_f32_16x16x32_bf16(
                                    a[i], b[j], acc[i][j], 0, 0, 0);
        }
        __syncthreads();
    }
    #pragma unroll
    for (int i = 0; i < 4; i++) {
        #pragma unroll
        for (int r = 0; r < 4; r++) {
            int m = m0 + wr*64 + i*16 + g*4 + r;
            int ss = m >> 8, rr = m & 255;
            #pragma unroll
            for (int j = 0; j < 4; j++) {
                int col = n0 + wc*64 + j*16 + ln15;
                int lc = col & 255;
                int h = lc >> 5, d = lc & 31;
                float val = acc[i][j][r];
                size_t qidx = (((size_t)ss*HEADS + h)*RDIM + rr)*DH + d;
                if (seg == 0)      qo[qidx] = f2bf(val * 0.17677669529663687f);
                else if (seg == 1) ko[qidx] = f2bf(val);
                else if (seg == 2) vo[qidx] = f2bf(val);
                else {
                    float x = val + bg[lc];
                    go[(size_t)m*CS + lc] = f2bf(1.f / (1.f + expf(-x)));
                }
            }
        }
    }
}

// ---- attention: swapped-QK^T MFMA flash, block per (s,h), 4 waves -------
// Wave handles 4 q-tiles of 16 rows, FULLY UNROLLED with a 1-deep pb
// software pipeline: iteration qt lands pb regs loaded a full iteration
// earlier (no vmem stall), then immediately issues qt+1's loads so they
// complete under QK^T+softmax+PV. PBlds triple-duty: pb tile / P / O bounce.
__global__ __launch_bounds__(256, 2) void attn_kernel(
        const unsigned short* __restrict__ q, const unsigned short* __restrict__ k,
        const unsigned short* __restrict__ v, const unsigned short* __restrict__ pb,
        const float* __restrict__ mask, unsigned short* __restrict__ o) {
    __shared__ alignas(16) unsigned short Klds[256][40];
    __shared__ alignas(16) unsigned short Vtlds[32][264];
    __shared__ alignas(16) unsigned short PBlds[4][16][264];
    __shared__ float masklds[256];

    const int sh = blockIdx.x;                   // s*8 + h
    const int ss = sh >> 3, h = sh & 7;
    const int tid = threadIdx.x;
    const int lane = tid & 63, wid = tid >> 6;
    const int ln15 = lane & 15, g = lane >> 4;   // g in 0..3

    const unsigned short* kp = k + (size_t)sh * 8192;
    const unsigned short* vp = v + (size_t)sh * 8192;
    const unsigned short* pbh = pb + (size_t)h * ZROWS;
    // pb row base for this lane (row = q0+ln15), advanced by q0 per qt
    const unsigned short* pbrow0 = pbh + (size_t)(wid*64 + ln15)*RDIM;

    // ---- issue qt=0 pb loads first: overlap with K/V staging ----
    uint4 cur[8], nxt[8];
    #pragma unroll
    for (int j = 0; j < 8; j++)
        cur[j] = *(const uint4*)&pbrow0[j*32 + g*8];

    // ---- stage K and V^T to LDS ----
    #pragma unroll
    for (int i = 0; i < 4; i++) {
        int idx = tid + i*256;                   // chunk of 8 bf16, 0..1023
        int row = idx >> 2, col = (idx & 3) * 8; // row: k-index, col: d
        short8_t kv8 = *(const short8_t*)&kp[(size_t)row*DH + col];
        short8_t vv8 = *(const short8_t*)&vp[(size_t)row*DH + col];
        *(short8_t*)&Klds[row][col] = kv8;
        #pragma unroll
        for (int e = 0; e < 8; e++)
            Vtlds[col+e][row] = (unsigned short)vv8[e];
    }
    masklds[tid] = 1e9f * (mask[(size_t)ss*RDIM + tid] - 1.f);

    // ---- Q B-frags for the wave's 4 q-tiles (col=ln15=q, k=g*8 over d) --
    short8_t qfr[4];
    {
        const unsigned short* qp = q + (size_t)sh * 8192;
        #pragma unroll
        for (int qt = 0; qt < 4; qt++)
            qfr[qt] = *(const short8_t*)&qp[(size_t)(wid*64 + qt*16 + ln15)*DH + g*8];
    }
    __syncthreads();

    #pragma unroll
    for (int qt = 0; qt < 4; qt++) {
        const int q0 = wid*64 + qt*16;
        // ---- land pb_qt (loaded a full iteration ago) into LDS tile -----
        #pragma unroll
        for (int j = 0; j < 8; j++)
            *(uint4*)&PBlds[wid][ln15][j*32 + g*8] = cur[j];
        // ---- issue pb_{qt+1} loads: complete under this iteration -------
        if (qt < 3) {
            const unsigned short* pbn = pbrow0 + (size_t)(qt+1)*16*RDIM;
            #pragma unroll
            for (int j = 0; j < 8; j++)
                nxt[j] = *(const uint4*)&pbn[j*32 + g*8];
        }
        // ---- S^T = K . Q^T (LDS-only deps) ------------------------------
        f32x4 st[16];
        #pragma unroll
        for (int t = 0; t < 16; t++) {
            short8_t kf = *(const short8_t*)&Klds[t*16 + ln15][g*8];
            st[t] = __builtin_amdgcn_mfma_f32_16x16x32_bf16(
                        kf, qfr[qt], (f32x4){0.f,0.f,0.f,0.f}, 0, 0, 0);
        }
        // ---- bias: pb (LDS) + mask (bcast LDS) --------------------------
        #pragma unroll
        for (int t = 0; t < 16; t++) {
            uint2 p2 = *(const uint2*)&PBlds[wid][ln15][t*16 + g*4];
            float4 mk4 = *(const float4*)&masklds[t*16 + g*4];
            st[t][0] += bf2f((unsigned short)(p2.x & 0xffffu)) + mk4.x;
            st[t][1] += bf2f((unsigned short)(p2.x >> 16))     + mk4.y;
            st[t][2] += bf2f((unsigned short)(p2.y & 0xffffu)) + mk4.z;
            st[t][3] += bf2f((unsigned short)(p2.y >> 16))     + mk4.w;
        }
        // ---- single-pass softmax, in-lane + 2 shuffles across g ---------
        float mx = -INFINITY;
        #pragma unroll
        for (int t = 0; t < 16; t++) {
            float a = fmaxf(fmaxf(st[t][0], st[t][1]), fmaxf(st[t][2], st[t][3]));
            mx = fmaxf(mx, a);
        }
        mx = fmaxf(mx, __shfl_xor(mx, 16, 64));
        mx = fmaxf(mx, __shfl_xor(mx, 32, 64));
        float l = 0.f;
        #pragma unroll
        for (int t = 0; t < 16; t++) {
            #pragma unroll
            for (int r = 0; r < 4; r++) {
                float p = exp2f((st[t][r] - mx) * LOG2E);
                st[t][r] = p;
                l += p;
            }
        }
        l += __shfl_xor(l, 16, 64);
        l += __shfl_xor(l, 32, 64);
        float inv = 1.f / l;
        // ---- PV per 64-k chunk: P -> PBlds (b64), O^T += V^T . P^T ------
        f32x4 oacc[2];
        oacc[0] = (f32x4){0.f,0.f,0.f,0.f};
        oacc[1] = (f32x4){0.f,0.f,0.f,0.f};
        #pragma unroll
        for (int c = 0; c < 4; c++) {
            #pragma unroll
            for (int tc = 0; tc < 4; tc++) {
                int t = c*4 + tc;
                uint2 w;
                w.x = (unsigned)f2bf(st[t][0]) | ((unsigned)f2bf(st[t][1]) << 16);
                w.y = (unsigned)f2bf(st[t][2]) | ((unsigned)f2bf(st[t][3]) << 16);
                *(uint2*)&PBlds[wid][ln15][tc*16 + g*4] = w;
            }
            #pragma unroll
            for (int ks = 0; ks < 2; ks++) {
                short8_t pfr = *(const short8_t*)&PBlds[wid][ln15][ks*32 + g*8];
                #pragma unroll
                for (int dt = 0; dt < 2; dt++) {
                    short8_t vf = *(const short8_t*)&Vtlds[dt*16 + ln15][c*64 + ks*32 + g*8];
                    oacc[dt] = __builtin_amdgcn_mfma_f32_16x16x32_bf16(
                                   vf, pfr, oacc[dt], 0, 0, 0);
                }
            }
        }
        // ---- epilogue: O^T -> PBlds [q][d] -> coalesced 16B stores ------
        #pragma unroll
        for (int dt = 0; dt < 2; dt++) {
            uint2 w;
            w.x = (unsigned)f2bf(oacc[dt][0]*inv) | ((unsigned)f2bf(oacc[dt][1]*inv) << 16);
            w.y = (unsigned)f2bf(oacc[dt][2]*inv) | ((unsigned)f2bf(oacc[dt][3]*inv) << 16);
            *(uint2*)&PBlds[wid][ln15][dt*16 + g*4] = w;
        }
        {
            int qr = lane >> 2, dc = (lane & 3) * 8;
            short8_t ov = *(const short8_t*)&PBlds[wid][qr][dc];
            *(short8_t*)&o[((size_t)ss*RDIM + q0 + qr)*CS + h*DH + dc] = ov;
        }
        // ---- rotate pipeline regs (static under full unroll) ------------
        if (qt < 3) {
            #pragma unroll
            for (int j = 0; j < 8; j++) cur[j] = nxt[j];
        }
    }
}

// ------------- output projection (MFMA): out = (o .* g) @ wo + bo --------
__global__ __launch_bounds__(256, 2) void outproj_kernel(
        const unsigned short* __restrict__ ob, const unsigned short* __restrict__ gb,
        const unsigned short* __restrict__ wot, const float* __restrict__ bo,
        float* __restrict__ out) {
    __shared__ alignas(16) unsigned short As[128][72];
    __shared__ alignas(16) unsigned short Bs[128][72];
    const int m0 = blockIdx.x * 128;
    const int n0 = blockIdx.y * 128;             // 0 or 128
    const int tid = threadIdx.x;
    const int lane = tid & 63, wid = tid >> 6;
    const int ln15 = lane & 15, g = lane >> 4;
    const int wr = wid >> 1, wc = wid & 1;
    f32x4 acc[4][4];
    #pragma unroll
    for (int i = 0; i < 4; i++)
        #pragma unroll
        for (int j = 0; j < 4; j++) acc[i][j] = (f32x4){0.f,0.f,0.f,0.f};

    for (int k0 = 0; k0 < 256; k0 += 64) {
        #pragma unroll
        for (int c = 0; c < 4; c++) {
            int L = tid + c*256;
            int row = L >> 3, kc = (L & 7) * 8;
            short8_t ov = *(const short8_t*)&ob[(size_t)(m0+row)*256 + k0 + kc];
            short8_t gv = *(const short8_t*)&gb[(size_t)(m0+row)*256 + k0 + kc];
            short8_t pr;
            #pragma unroll
            for (int e = 0; e < 8; e++)
                pr[e] = (short)f2bf(bf2f((unsigned short)ov[e]) *
                                    bf2f((unsigned short)gv[e]));
            *(short8_t*)&As[row][kc] = pr;
            *(short8_t*)&Bs[row][kc] =
                *(const short8_t*)&wot[(size_t)(n0+row)*256 + k0 + kc];
        }
        __syncthreads();
        #pragma unroll
        for (int kk = 0; kk < 64; kk += 32) {
            short8_t a[4], b[4];
            #pragma unroll
            for (int i = 0; i < 4; i++) {
                a[i] = *(const short8_t*)&As[wr*64 + i*16 + ln15][kk + g*8];
                b[i] = *(const short8_t*)&Bs[wc*64 + i*16 + ln15][kk + g*8];
            }
            #pragma unroll
            for (int i = 0; i < 4; i++)
                #pragma unroll
                for (int j = 0; j < 4; j++)
                    acc[i][j] = __builtin_amdgcn_mfma_f32_16x16x32_bf16(
                                    a[i], b[j], acc[i][j], 0, 0, 0);
        }
        __syncthreads();
    }
    #pragma unroll
    for (int i = 0; i < 4; i++) {
        #pragma unroll
        for (int r = 0; r < 4; r++) {
            int m = m0 + wr*64 + i*16 + g*4 + r;
            #pragma unroll
            for (int j = 0; j < 4; j++) {
                int col = n0 + wc*64 + j*16 + ln15;
                out[(size_t)m*CS + col] = acc[i][j][r] + bo[col];
            }
        }
    }
}

extern "C" void kernel_launch(void* const* d_in, const int* in_sizes, int n_in,
                              void* d_out, int out_size, void* d_ws, size_t ws_size,
                              hipStream_t stream) {
    const float* s      = (const float*)d_in[0];
    const float* z      = (const float*)d_in[1];
    const float* mask   = (const float*)d_in[2];
    const float* ln_s_w = (const float*)d_in[3];
    const float* ln_s_b = (const float*)d_in[4];
    const float* ln_z_w = (const float*)d_in[5];
    const float* ln_z_b = (const float*)d_in[6];
    const float* w_z    = (const float*)d_in[7];
    const float* w_q    = (const float*)d_in[8];
    const float* w_k    = (const float*)d_in[9];
    const float* w_v    = (const float*)d_in[10];
    const float* w_g    = (const float*)d_in[11];
    const float* b_g    = (const float*)d_in[12];
    const float* w_o    = (const float*)d_in[13];
    const float* b_o    = (const float*)d_in[14];
    float* out = (float*)d_out;
    float* ws  = (float*)d_ws;

    // Workspace layout (float units; bf16 buffers cast):
    unsigned short* snb = (unsigned short*)ws;                    // 8388608 shorts
    unsigned short* wtb = (unsigned short*)(ws + 4194304);        // 262144 shorts
    unsigned short* wot = (unsigned short*)(ws + 4194304+131072); // 65536 shorts
    unsigned short* pbb = (unsigned short*)(ws + 4194304+131072+32768); // 524288 shorts (bf16)
    float* after_pb = ws + 4194304 + 131072 + 32768 + 262144;
    unsigned short* qb  = (unsigned short*)after_pb;              // 8388608 shorts each
    unsigned short* kb  = qb + 8388608;
    unsigned short* vb  = kb + 8388608;
    unsigned short* gbuf= vb + 8388608;
    unsigned short* obuf= gbuf + 8388608;

    ln_s_kernel<<<MROWS/4, 256, 0, stream>>>(s, ln_s_w, ln_s_b, snb);
    ln_z_pb_kernel<<<ZROWS/4, 256, 0, stream>>>(z, ln_z_w, ln_z_b, w_z, pbb);
    wconv_kernel<<<dim3(4,4,5), 256, 0, stream>>>(w_q, w_k, w_v, w_g, w_o, wtb, wot);
    qkvg_kernel<<<dim3(MROWS/128, 8), 256, 0, stream>>>(snb, wtb, b_g, qb, kb, vb, gbuf);
    attn_kernel<<<SDIM*HEADS, 256, 0, stream>>>(qb, kb, vb, pbb, mask, obuf);
    outproj_kernel<<<dim3(MROWS/128, 2), 256, 0, stream>>>(obuf, gbuf, wot, b_o, out);
}

// Round 12
// 187.937 us; speedup vs baseline: 1.6662x; 1.1051x over previous
//
#include <hip/hip_runtime.h>
#include <math.h>

#define CS 256
#define CZ 128
#define HEADS 8
#define DH 32
#define SDIM 128
#define RDIM 256
#define MROWS (SDIM*RDIM)   // 32768
#define ZROWS (RDIM*RDIM)   // 65536
#define EPSF 1e-5f
#define LOG2E 1.44269504088896340736f

typedef __attribute__((ext_vector_type(8))) short short8_t;   // 8 bf16 (4 VGPRs)
typedef __attribute__((ext_vector_type(4))) float f32x4;

__device__ __forceinline__ float waveReduceSum(float v) {
    #pragma unroll
    for (int off = 32; off > 0; off >>= 1) v += __shfl_xor(v, off, 64);
    return v;
}

__device__ __forceinline__ unsigned short f2bf(float f) {
    unsigned u = __float_as_uint(f);
    unsigned r = (u + 0x7fffu + ((u >> 16) & 1u)) >> 16;   // RNE
    return (unsigned short)r;
}

__device__ __forceinline__ float bf2f(unsigned short u) {
    return __uint_as_float(((unsigned)u) << 16);
}

// ---------------- LayerNorm of s: one wave per row of 256, bf16 out ------
__global__ __launch_bounds__(256) void ln_s_kernel(const float* __restrict__ s,
        const float* __restrict__ w, const float* __restrict__ b,
        unsigned short* __restrict__ snb) {
    int wid = threadIdx.x >> 6;
    int lane = threadIdx.x & 63;
    int row = blockIdx.x * 4 + wid;              // < 32768
    const float4 v = ((const float4*)(s + (size_t)row * CS))[lane];
    float sum = waveReduceSum(v.x + v.y + v.z + v.w);
    float sq  = waveReduceSum(v.x*v.x + v.y*v.y + v.z*v.z + v.w*v.w);
    float mean = sum * (1.f/CS);
    float var  = sq * (1.f/CS) - mean*mean;
    float rstd = rsqrtf(var + EPSF);
    const float4 wv = ((const float4*)w)[lane];
    const float4 bv = ((const float4*)b)[lane];
    ushort4 o;
    o.x = f2bf((v.x-mean)*rstd*wv.x + bv.x);
    o.y = f2bf((v.y-mean)*rstd*wv.y + bv.y);
    o.z = f2bf((v.z-mean)*rstd*wv.z + bv.z);
    o.w = f2bf((v.w-mean)*rstd*wv.w + bv.w);
    ((ushort4*)(snb + (size_t)row * CS))[lane] = o;
}

// ------- LayerNorm of z + pair bias: one wave per (q,k) row of 128 -------
// writes pb[h][q][k] as bf16
__global__ __launch_bounds__(256) void ln_z_pb_kernel(const float* __restrict__ z,
        const float* __restrict__ w, const float* __restrict__ b,
        const float* __restrict__ wz, unsigned short* __restrict__ pb) {
    int wid = threadIdx.x >> 6;
    int lane = threadIdx.x & 63;
    int row = blockIdx.x * 4 + wid;              // row = q*256 + k, < 65536
    const float2 v = ((const float2*)(z + (size_t)row * CZ))[lane];
    float sum = waveReduceSum(v.x + v.y);
    float sq  = waveReduceSum(v.x*v.x + v.y*v.y);
    float mean = sum * (1.f/CZ);
    float var  = sq * (1.f/CZ) - mean*mean;
    float rstd = rsqrtf(var + EPSF);
    const float2 wv = ((const float2*)w)[lane];
    const float2 bv = ((const float2*)b)[lane];
    float n0 = (v.x-mean)*rstd*wv.x + bv.x;
    float n1 = (v.y-mean)*rstd*wv.y + bv.y;
    const float* wz0 = wz + (size_t)(lane*2) * HEADS;   // wz: [128][8]
    float ph[8];
    #pragma unroll
    for (int h = 0; h < 8; h++) ph[h] = n0*wz0[h] + n1*wz0[HEADS + h];
    #pragma unroll
    for (int h = 0; h < 8; h++) ph[h] = waveReduceSum(ph[h]);
    if (lane == 0) {
        #pragma unroll
        for (int h = 0; h < 8; h++)
            pb[(size_t)h*ZROWS + row] = f2bf(ph[h]);   // [h][q][k] bf16
    }
}

// ----- weight convert: w[k][n] fp32 -> wt[n][k] bf16 (n-major for B-frag) -
__global__ __launch_bounds__(256) void wconv_kernel(const float* __restrict__ wq,
        const float* __restrict__ wk, const float* __restrict__ wv,
        const float* __restrict__ wg, const float* __restrict__ wo,
        unsigned short* __restrict__ wtb, unsigned short* __restrict__ wot) {
    __shared__ float T[64][65];
    const int wi = blockIdx.z;
    const float* W = (wi==0)?wq:(wi==1)?wk:(wi==2)?wv:(wi==3)?wg:wo;
    unsigned short* O = (wi<4) ? (wtb + (size_t)wi*65536) : wot;
    const int bk = blockIdx.x * 64, bn = blockIdx.y * 64;
    const int tx = threadIdx.x & 63, tg = threadIdx.x >> 6;
    #pragma unroll
    for (int i = 0; i < 16; i++) {
        int r = tg*16 + i;
        T[r][tx] = W[(size_t)(bk+r)*256 + bn + tx];
    }
    __syncthreads();
    #pragma unroll
    for (int i = 0; i < 16; i++) {
        int r = tg*16 + i;
        O[(size_t)(bn+r)*256 + bk + tx] = f2bf(T[tx][r]);
    }
}

// ------------- QKVG projection GEMM (MFMA): M=32768, K=256, N=1024 -------
__global__ __launch_bounds__(256, 2) void qkvg_kernel(
        const unsigned short* __restrict__ snb,
        const unsigned short* __restrict__ wtb,
        const float* __restrict__ bg,
        unsigned short* __restrict__ qo, unsigned short* __restrict__ ko,
        unsigned short* __restrict__ vo, unsigned short* __restrict__ go) {
    __shared__ alignas(16) unsigned short As[128][72];   // pad 64->72: 2-way only
    __shared__ alignas(16) unsigned short Bs[128][72];
    const int m0 = blockIdx.x * 128;
    const int n0 = blockIdx.y * 128;             // 0..896
    const int seg = n0 >> 8;
    const int nseg = n0 & 255;                   // 0 or 128
    const unsigned short* wt = wtb + (size_t)seg * 65536;
    const int tid = threadIdx.x;
    const int lane = tid & 63, wid = tid >> 6;
    const int ln15 = lane & 15, g = lane >> 4;
    const int wr = wid >> 1, wc = wid & 1;
    f32x4 acc[4][4];
    #pragma unroll
    for (int i = 0; i < 4; i++)
        #pragma unroll
        for (int j = 0; j < 4; j++) acc[i][j] = (f32x4){0.f,0.f,0.f,0.f};

    for (int k0 = 0; k0 < 256; k0 += 64) {
        #pragma unroll
        for (int c = 0; c < 4; c++) {
            int L = tid + c*256;                 // 0..1023 chunks of 8 bf16
            int row = L >> 3, kc = (L & 7) * 8;
            *(short8_t*)&As[row][kc] =
                *(const short8_t*)&snb[(size_t)(m0+row)*256 + k0 + kc];
            *(short8_t*)&Bs[row][kc] =
                *(const short8_t*)&wt[(size_t)(nseg+row)*256 + k0 + kc];
        }
        __syncthreads();
        #pragma unroll
        for (int kk = 0; kk < 64; kk += 32) {
            short8_t a[4], b[4];
            #pragma unroll
            for (int i = 0; i < 4; i++) {
                a[i] = *(const short8_t*)&As[wr*64 + i*16 + ln15][kk + g*8];
                b[i] = *(const short8_t*)&Bs[wc*64 + i*16 + ln15][kk + g*8];
            }
            #pragma unroll
            for (int i = 0; i < 4; i++)
                #pragma unroll
                for (int j = 0; j < 4; j++)
                    acc[i][j] = __builtin_amdgcn_mfma_f32_16x16x32_bf16(
                                    a[i], b[j], acc[i][j], 0, 0, 0);
        }
        __syncthreads();
    }
    #pragma unroll
    for (int i = 0; i < 4; i++) {
        #pragma unroll
        for (int r = 0; r < 4; r++) {
            int m = m0 + wr*64 + i*16 + g*4 + r;
            int ss = m >> 8, rr = m & 255;
            #pragma unroll
            for (int j = 0; j < 4; j++) {
                int col = n0 + wc*64 + j*16 + ln15;
                int lc = col & 255;
                int h = lc >> 5, d = lc & 31;
                float val = acc[i][j][r];
                size_t qidx = (((size_t)ss*HEADS + h)*RDIM + rr)*DH + d;
                if (seg == 0)      qo[qidx] = f2bf(val * 0.17677669529663687f);
                else if (seg == 1) ko[qidx] = f2bf(val);
                else if (seg == 2) vo[qidx] = f2bf(val);
                else {
                    float x = val + bg[lc];
                    go[(size_t)m*CS + lc] = f2bf(1.f / (1.f + expf(-x)));
                }
            }
        }
    }
}

// ---- attention: swapped-QK^T MFMA flash, block per (s,h), 4 waves -------
// pb staged via async global_load_lds into per-wave linear LDS with a
// 16B-chunk XOR swizzle s(n)=n^((n>>5)&7) applied on BOTH the per-lane
// global source (write side) and the ds_read address (read side) -> 2-way
// banks, zero VGPR pipeline state (fixes r11's spill-driven 142MB writes).
__global__ __launch_bounds__(256, 2) void attn_kernel(
        const unsigned short* __restrict__ q, const unsigned short* __restrict__ k,
        const unsigned short* __restrict__ v, const unsigned short* __restrict__ pb,
        const float* __restrict__ mask, unsigned short* __restrict__ o) {
    __shared__ alignas(16) unsigned short Klds[256][40];
    __shared__ alignas(16) unsigned short Vtlds[32][264];
    __shared__ alignas(16) unsigned short PBpb[4][4096];   // per-wave pb tile (swizzled)
    __shared__ alignas(16) unsigned short Plds[4][16][72]; // P / O bounce
    __shared__ float masklds[256];

    const int sh = blockIdx.x;                   // s*8 + h
    const int ss = sh >> 3, h = sh & 7;
    const int tid = threadIdx.x;
    const int lane = tid & 63, wid = tid >> 6;
    const int ln15 = lane & 15, g = lane >> 4;   // g in 0..3

    const unsigned short* kp = k + (size_t)sh * 8192;
    const unsigned short* vp = v + (size_t)sh * 8192;
    const unsigned short* pbh = pb + (size_t)h * ZROWS;
    unsigned short* pbw = &PBpb[wid][0];

    // ---- async-stage pb tile qt=0 (before K/V staging: long cover) ------
    {
        const unsigned short* pbase = pbh + (size_t)(wid*64) * RDIM;
        #pragma unroll
        for (int j = 0; j < 8; j++) {
            int w = j*64 + lane;
            int n = w ^ ((w >> 5) & 7);          // involution chunk swizzle
            const unsigned short* src = pbase + (n >> 5) * RDIM + (n & 31) * 8;
            __builtin_amdgcn_global_load_lds(
                (const __attribute__((address_space(1))) unsigned int*)src,
                (__attribute__((address_space(3))) unsigned int*)(pbw + j*512),
                16, 0, 0);
        }
    }

    // ---- stage K and V^T to LDS ----
    #pragma unroll
    for (int i = 0; i < 4; i++) {
        int idx = tid + i*256;                   // chunk of 8 bf16, 0..1023
        int row = idx >> 2, col = (idx & 3) * 8; // row: k-index, col: d
        short8_t kv8 = *(const short8_t*)&kp[(size_t)row*DH + col];
        short8_t vv8 = *(const short8_t*)&vp[(size_t)row*DH + col];
        *(short8_t*)&Klds[row][col] = kv8;
        #pragma unroll
        for (int e = 0; e < 8; e++)
            Vtlds[col+e][row] = (unsigned short)vv8[e];
    }
    masklds[tid] = 1e9f * (mask[(size_t)ss*RDIM + tid] - 1.f);

    // ---- Q B-frags for the wave's 4 q-tiles (col=ln15=q, k=g*8 over d) --
    short8_t qfr[4];
    {
        const unsigned short* qp = q + (size_t)sh * 8192;
        #pragma unroll
        for (int qt = 0; qt < 4; qt++)
            qfr[qt] = *(const short8_t*)&qp[(size_t)(wid*64 + qt*16 + ln15)*DH + g*8];
    }
    __syncthreads();

    #pragma unroll 1
    for (int qt = 0; qt < 4; qt++) {
        const int q0 = wid*64 + qt*16;
        // ---- S^T = K . Q^T (LDS deps only; pb gll still in flight) ------
        f32x4 st[16];
        #pragma unroll
        for (int t = 0; t < 16; t++) {
            short8_t kf = *(const short8_t*)&Klds[t*16 + ln15][g*8];
            st[t] = __builtin_amdgcn_mfma_f32_16x16x32_bf16(
                        kf, qfr[qt], (f32x4){0.f,0.f,0.f,0.f}, 0, 0, 0);
        }
        // ---- pb landed? then bias: pb (swizzled LDS) + mask (bcast) -----
        asm volatile("s_waitcnt vmcnt(0)" ::: "memory");
        __builtin_amdgcn_sched_barrier(0);
        #pragma unroll
        for (int t = 0; t < 16; t++) {
            int n = ln15*32 + t*2 + (g >> 1);
            int m = n ^ (ln15 & 7);
            uint2 p2 = *(const uint2*)&pbw[m*8 + (g & 1)*4];
            float4 mk4 = *(const float4*)&masklds[t*16 + g*4];
            st[t][0] += bf2f((unsigned short)(p2.x & 0xffffu)) + mk4.x;
            st[t][1] += bf2f((unsigned short)(p2.x >> 16))     + mk4.y;
            st[t][2] += bf2f((unsigned short)(p2.y & 0xffffu)) + mk4.z;
            st[t][3] += bf2f((unsigned short)(p2.y >> 16))     + mk4.w;
        }
        // ---- single-pass softmax, in-lane + 2 shuffles across g ---------
        float mx = -INFINITY;
        #pragma unroll
        for (int t = 0; t < 16; t++) {
            float a = fmaxf(fmaxf(st[t][0], st[t][1]), fmaxf(st[t][2], st[t][3]));
            mx = fmaxf(mx, a);
        }
        mx = fmaxf(mx, __shfl_xor(mx, 16, 64));
        mx = fmaxf(mx, __shfl_xor(mx, 32, 64));
        float l = 0.f;
        #pragma unroll
        for (int t = 0; t < 16; t++) {
            #pragma unroll
            for (int r = 0; r < 4; r++) {
                float p = exp2f((st[t][r] - mx) * LOG2E);
                st[t][r] = p;
                l += p;
            }
        }
        l += __shfl_xor(l, 16, 64);
        l += __shfl_xor(l, 32, 64);
        float inv = 1.f / l;
        // ---- issue next tile's pb gll (buffer free; covers under PV) ----
        if (qt < 3) {
            const unsigned short* pbase = pbh + (size_t)(q0 + 16) * RDIM;
            #pragma unroll
            for (int j = 0; j < 8; j++) {
                int w = j*64 + lane;
                int n = w ^ ((w >> 5) & 7);
                const unsigned short* src = pbase + (n >> 5) * RDIM + (n & 31) * 8;
                __builtin_amdgcn_global_load_lds(
                    (const __attribute__((address_space(1))) unsigned int*)src,
                    (__attribute__((address_space(3))) unsigned int*)(pbw + j*512),
                    16, 0, 0);
            }
        }
        // ---- PV per 64-k chunk: P -> Plds (b64), O^T += V^T . P^T -------
        f32x4 oacc[2];
        oacc[0] = (f32x4){0.f,0.f,0.f,0.f};
        oacc[1] = (f32x4){0.f,0.f,0.f,0.f};
        #pragma unroll
        for (int c = 0; c < 4; c++) {
            #pragma unroll
            for (int tc = 0; tc < 4; tc++) {
                int t = c*4 + tc;
                uint2 w;
                w.x = (unsigned)f2bf(st[t][0]) | ((unsigned)f2bf(st[t][1]) << 16);
                w.y = (unsigned)f2bf(st[t][2]) | ((unsigned)f2bf(st[t][3]) << 16);
                *(uint2*)&Plds[wid][ln15][tc*16 + g*4] = w;
            }
            #pragma unroll
            for (int ks = 0; ks < 2; ks++) {
                short8_t pfr = *(const short8_t*)&Plds[wid][ln15][ks*32 + g*8];
                #pragma unroll
                for (int dt = 0; dt < 2; dt++) {
                    short8_t vf = *(const short8_t*)&Vtlds[dt*16 + ln15][c*64 + ks*32 + g*8];
                    oacc[dt] = __builtin_amdgcn_mfma_f32_16x16x32_bf16(
                                   vf, pfr, oacc[dt], 0, 0, 0);
                }
            }
        }
        // ---- epilogue: O^T -> Plds [q][d] -> coalesced 16B stores -------
        #pragma unroll
        for (int dt = 0; dt < 2; dt++) {
            uint2 w;
            w.x = (unsigned)f2bf(oacc[dt][0]*inv) | ((unsigned)f2bf(oacc[dt][1]*inv) << 16);
            w.y = (unsigned)f2bf(oacc[dt][2]*inv) | ((unsigned)f2bf(oacc[dt][3]*inv) << 16);
            *(uint2*)&Plds[wid][ln15][dt*16 + g*4] = w;
        }
        {
            int qr = lane >> 2, dc = (lane & 3) * 8;
            short8_t ov = *(const short8_t*)&Plds[wid][qr][dc];
            *(short8_t*)&o[((size_t)ss*RDIM + q0 + qr)*CS + h*DH + dc] = ov;
        }
    }
}

// ------------- output projection (MFMA): out = (o .* g) @ wo + bo --------
__global__ __launch_bounds__(256, 2) void outproj_kernel(
        const unsigned short* __restrict__ ob, const unsigned short* __restrict__ gb,
        const unsigned short* __restrict__ wot, const float* __restrict__ bo,
        float* __restrict__ out) {
    __shared__ alignas(16) unsigned short As[128][72];
    __shared__ alignas(16) unsigned short Bs[128][72];
    const int m0 = blockIdx.x * 128;
    const int n0 = blockIdx.y * 128;             // 0 or 128
    const int tid = threadIdx.x;
    const int lane = tid & 63, wid = tid >> 6;
    const int ln15 = lane & 15, g = lane >> 4;
    const int wr = wid >> 1, wc = wid & 1;
    f32x4 acc[4][4];
    #pragma unroll
    for (int i = 0; i < 4; i++)
        #pragma unroll
        for (int j = 0; j < 4; j++) acc[i][j] = (f32x4){0.f,0.f,0.f,0.f};

    for (int k0 = 0; k0 < 256; k0 += 64) {
        #pragma unroll
        for (int c = 0; c < 4; c++) {
            int L = tid + c*256;
            int row = L >> 3, kc = (L & 7) * 8;
            short8_t ov = *(const short8_t*)&ob[(size_t)(m0+row)*256 + k0 + kc];
            short8_t gv = *(const short8_t*)&gb[(size_t)(m0+row)*256 + k0 + kc];
            short8_t pr;
            #pragma unroll
            for (int e = 0; e < 8; e++)
                pr[e] = (short)f2bf(bf2f((unsigned short)ov[e]) *
                                    bf2f((unsigned short)gv[e]));
            *(short8_t*)&As[row][kc] = pr;
            *(short8_t*)&Bs[row][kc] =
                *(const short8_t*)&wot[(size_t)(n0+row)*256 + k0 + kc];
        }
        __syncthreads();
        #pragma unroll
        for (int kk = 0; kk < 64; kk += 32) {
            short8_t a[4], b[4];
            #pragma unroll
            for (int i = 0; i < 4; i++) {
                a[i] = *(const short8_t*)&As[wr*64 + i*16 + ln15][kk + g*8];
                b[i] = *(const short8_t*)&Bs[wc*64 + i*16 + ln15][kk + g*8];
            }
            #pragma unroll
            for (int i = 0; i < 4; i++)
                #pragma unroll
                for (int j = 0; j < 4; j++)
                    acc[i][j] = __builtin_amdgcn_mfma_f32_16x16x32_bf16(
                                    a[i], b[j], acc[i][j], 0, 0, 0);
        }
        __syncthreads();
    }
    #pragma unroll
    for (int i = 0; i < 4; i++) {
        #pragma unroll
        for (int r = 0; r < 4; r++) {
            int m = m0 + wr*64 + i*16 + g*4 + r;
            #pragma unroll
            for (int j = 0; j < 4; j++) {
                int col = n0 + wc*64 + j*16 + ln15;
                out[(size_t)m*CS + col] = acc[i][j][r] + bo[col];
            }
        }
    }
}

extern "C" void kernel_launch(void* const* d_in, const int* in_sizes, int n_in,
                              void* d_out, int out_size, void* d_ws, size_t ws_size,
                              hipStream_t stream) {
    const float* s      = (const float*)d_in[0];
    const float* z      = (const float*)d_in[1];
    const float* mask   = (const float*)d_in[2];
    const float* ln_s_w = (const float*)d_in[3];
    const float* ln_s_b = (const float*)d_in[4];
    const float* ln_z_w = (const float*)d_in[5];
    const float* ln_z_b = (const float*)d_in[6];
    const float* w_z    = (const float*)d_in[7];
    const float* w_q    = (const float*)d_in[8];
    const float* w_k    = (const float*)d_in[9];
    const float* w_v    = (const float*)d_in[10];
    const float* w_g    = (const float*)d_in[11];
    const float* b_g    = (const float*)d_in[12];
    const float* w_o    = (const float*)d_in[13];
    const float* b_o    = (const float*)d_in[14];
    float* out = (float*)d_out;
    float* ws  = (float*)d_ws;

    // Workspace layout (float units; bf16 buffers cast):
    unsigned short* snb = (unsigned short*)ws;                    // 8388608 shorts
    unsigned short* wtb = (unsigned short*)(ws + 4194304);        // 262144 shorts
    unsigned short* wot = (unsigned short*)(ws + 4194304+131072); // 65536 shorts
    unsigned short* pbb = (unsigned short*)(ws + 4194304+131072+32768); // 524288 shorts (bf16)
    float* after_pb = ws + 4194304 + 131072 + 32768 + 262144;
    unsigned short* qb  = (unsigned short*)after_pb;              // 8388608 shorts each
    unsigned short* kb  = qb + 8388608;
    unsigned short* vb  = kb + 8388608;
    unsigned short* gbuf= vb + 8388608;
    unsigned short* obuf= gbuf + 8388608;

    ln_s_kernel<<<MROWS/4, 256, 0, stream>>>(s, ln_s_w, ln_s_b, snb);
    ln_z_pb_kernel<<<ZROWS/4, 256, 0, stream>>>(z, ln_z_w, ln_z_b, w_z, pbb);
    wconv_kernel<<<dim3(4,4,5), 256, 0, stream>>>(w_q, w_k, w_v, w_g, w_o, wtb, wot);
    qkvg_kernel<<<dim3(MROWS/128, 8), 256, 0, stream>>>(snb, wtb, b_g, qb, kb, vb, gbuf);
    attn_kernel<<<SDIM*HEADS, 256, 0, stream>>>(qb, kb, vb, pbb, mask, obuf);
    outproj_kernel<<<dim3(MROWS/128, 2), 256, 0, stream>>>(obuf, gbuf, wot, b_o, out);
}

// Round 13
// 183.915 us; speedup vs baseline: 1.7027x; 1.0219x over previous
//
#include <hip/hip_runtime.h>
#include <math.h>

#define CS 256
#define CZ 128
#define HEADS 8
#define DH 32
#define SDIM 128
#define RDIM 256
#define MROWS (SDIM*RDIM)   // 32768
#define ZROWS (RDIM*RDIM)   // 65536
#define EPSF 1e-5f
#define LOG2E 1.44269504088896340736f

typedef __attribute__((ext_vector_type(8))) short short8_t;   // 8 bf16 (4 VGPRs)
typedef __attribute__((ext_vector_type(4))) float f32x4;

__device__ __forceinline__ float waveReduceSum(float v) {
    #pragma unroll
    for (int off = 32; off > 0; off >>= 1) v += __shfl_xor(v, off, 64);
    return v;
}

__device__ __forceinline__ unsigned short f2bf(float f) {
    unsigned u = __float_as_uint(f);
    unsigned r = (u + 0x7fffu + ((u >> 16) & 1u)) >> 16;   // RNE
    return (unsigned short)r;
}

__device__ __forceinline__ float bf2f(unsigned short u) {
    return __uint_as_float(((unsigned)u) << 16);
}

// packed bf16 convert: lo = a, hi = b (HW RNE, 1 instruction)
__device__ __forceinline__ unsigned cvt_pk_bf16(float a, float b) {
    unsigned r;
    asm("v_cvt_pk_bf16_f32 %0, %1, %2" : "=v"(r) : "v"(a), "v"(b));
    return r;
}

// ---------------- LayerNorm of s: one wave per row of 256, bf16 out ------
__global__ __launch_bounds__(256) void ln_s_kernel(const float* __restrict__ s,
        const float* __restrict__ w, const float* __restrict__ b,
        unsigned short* __restrict__ snb) {
    int wid = threadIdx.x >> 6;
    int lane = threadIdx.x & 63;
    int row = blockIdx.x * 4 + wid;              // < 32768
    const float4 v = ((const float4*)(s + (size_t)row * CS))[lane];
    float sum = waveReduceSum(v.x + v.y + v.z + v.w);
    float sq  = waveReduceSum(v.x*v.x + v.y*v.y + v.z*v.z + v.w*v.w);
    float mean = sum * (1.f/CS);
    float var  = sq * (1.f/CS) - mean*mean;
    float rstd = rsqrtf(var + EPSF);
    const float4 wv = ((const float4*)w)[lane];
    const float4 bv = ((const float4*)b)[lane];
    ushort4 o;
    o.x = f2bf((v.x-mean)*rstd*wv.x + bv.x);
    o.y = f2bf((v.y-mean)*rstd*wv.y + bv.y);
    o.z = f2bf((v.z-mean)*rstd*wv.z + bv.z);
    o.w = f2bf((v.w-mean)*rstd*wv.w + bv.w);
    ((ushort4*)(snb + (size_t)row * CS))[lane] = o;
}

// ------- LayerNorm of z + pair bias: one wave per (q,k) row of 128 -------
// writes pb[h][q][k] as bf16
__global__ __launch_bounds__(256) void ln_z_pb_kernel(const float* __restrict__ z,
        const float* __restrict__ w, const float* __restrict__ b,
        const float* __restrict__ wz, unsigned short* __restrict__ pb) {
    int wid = threadIdx.x >> 6;
    int lane = threadIdx.x & 63;
    int row = blockIdx.x * 4 + wid;              // row = q*256 + k, < 65536
    const float2 v = ((const float2*)(z + (size_t)row * CZ))[lane];
    float sum = waveReduceSum(v.x + v.y);
    float sq  = waveReduceSum(v.x*v.x + v.y*v.y);
    float mean = sum * (1.f/CZ);
    float var  = sq * (1.f/CZ) - mean*mean;
    float rstd = rsqrtf(var + EPSF);
    const float2 wv = ((const float2*)w)[lane];
    const float2 bv = ((const float2*)b)[lane];
    float n0 = (v.x-mean)*rstd*wv.x + bv.x;
    float n1 = (v.y-mean)*rstd*wv.y + bv.y;
    const float* wz0 = wz + (size_t)(lane*2) * HEADS;   // wz: [128][8]
    float ph[8];
    #pragma unroll
    for (int h = 0; h < 8; h++) ph[h] = n0*wz0[h] + n1*wz0[HEADS + h];
    #pragma unroll
    for (int h = 0; h < 8; h++) ph[h] = waveReduceSum(ph[h]);
    if (lane == 0) {
        #pragma unroll
        for (int h = 0; h < 8; h++)
            pb[(size_t)h*ZROWS + row] = f2bf(ph[h]);   // [h][q][k] bf16
    }
}

// ----- weight convert: w[k][n] fp32 -> wt[n][k] bf16 (n-major for B-frag) -
__global__ __launch_bounds__(256) void wconv_kernel(const float* __restrict__ wq,
        const float* __restrict__ wk, const float* __restrict__ wv,
        const float* __restrict__ wg, const float* __restrict__ wo,
        unsigned short* __restrict__ wtb, unsigned short* __restrict__ wot) {
    __shared__ float T[64][65];
    const int wi = blockIdx.z;
    const float* W = (wi==0)?wq:(wi==1)?wk:(wi==2)?wv:(wi==3)?wg:wo;
    unsigned short* O = (wi<4) ? (wtb + (size_t)wi*65536) : wot;
    const int bk = blockIdx.x * 64, bn = blockIdx.y * 64;
    const int tx = threadIdx.x & 63, tg = threadIdx.x >> 6;
    #pragma unroll
    for (int i = 0; i < 16; i++) {
        int r = tg*16 + i;
        T[r][tx] = W[(size_t)(bk+r)*256 + bn + tx];
    }
    __syncthreads();
    #pragma unroll
    for (int i = 0; i < 16; i++) {
        int r = tg*16 + i;
        O[(size_t)(bn+r)*256 + bk + tx] = f2bf(T[tx][r]);
    }
}

// ------------- QKVG projection GEMM (MFMA): M=32768, K=256, N=1024 -------
// blockIdx.x XCD-swizzled: each XCD owns a contiguous 2MB A-panel that
// stays L2-resident across the 8 n-passes.
__global__ __launch_bounds__(256, 2) void qkvg_kernel(
        const unsigned short* __restrict__ snb,
        const unsigned short* __restrict__ wtb,
        const float* __restrict__ bg,
        unsigned short* __restrict__ qo, unsigned short* __restrict__ ko,
        unsigned short* __restrict__ vo, unsigned short* __restrict__ go) {
    __shared__ alignas(16) unsigned short As[128][72];   // pad 64->72: 2-way only
    __shared__ alignas(16) unsigned short Bs[128][72];
    const int bx = blockIdx.x;
    const int mblk = (bx & 7) * 32 + (bx >> 3);  // xcd = bx%8 -> contiguous m-chunk
    const int m0 = mblk * 128;
    const int n0 = blockIdx.y * 128;             // 0..896
    const int seg = n0 >> 8;
    const int nseg = n0 & 255;                   // 0 or 128
    const unsigned short* wt = wtb + (size_t)seg * 65536;
    const int tid = threadIdx.x;
    const int lane = tid & 63, wid = tid >> 6;
    const int ln15 = lane & 15, g = lane >> 4;
    const int wr = wid >> 1, wc = wid & 1;
    f32x4 acc[4][4];
    #pragma unroll
    for (int i = 0; i < 4; i++)
        #pragma unroll
        for (int j = 0; j < 4; j++) acc[i][j] = (f32x4){0.f,0.f,0.f,0.f};

    for (int k0 = 0; k0 < 256; k0 += 64) {
        #pragma unroll
        for (int c = 0; c < 4; c++) {
            int L = tid + c*256;                 // 0..1023 chunks of 8 bf16
            int row = L >> 3, kc = (L & 7) * 8;
            *(short8_t*)&As[row][kc] =
                *(const short8_t*)&snb[(size_t)(m0+row)*256 + k0 + kc];
            *(short8_t*)&Bs[row][kc] =
                *(const short8_t*)&wt[(size_t)(nseg+row)*256 + k0 + kc];
        }
        __syncthreads();
        #pragma unroll
        for (int kk = 0; kk < 64; kk += 32) {
            short8_t a[4], b[4];
            #pragma unroll
            for (int i = 0; i < 4; i++) {
                a[i] = *(const short8_t*)&As[wr*64 + i*16 + ln15][kk + g*8];
                b[i] = *(const short8_t*)&Bs[wc*64 + i*16 + ln15][kk + g*8];
            }
            #pragma unroll
            for (int i = 0; i < 4; i++)
                #pragma unroll
                for (int j = 0; j < 4; j++)
                    acc[i][j] = __builtin_amdgcn_mfma_f32_16x16x32_bf16(
                                    a[i], b[j], acc[i][j], 0, 0, 0);
        }
        __syncthreads();
    }
    #pragma unroll
    for (int i = 0; i < 4; i++) {
        #pragma unroll
        for (int r = 0; r < 4; r++) {
            int m = m0 + wr*64 + i*16 + g*4 + r;
            int ss = m >> 8, rr = m & 255;
            #pragma unroll
            for (int j = 0; j < 4; j++) {
                int col = n0 + wc*64 + j*16 + ln15;
                int lc = col & 255;
                int h = lc >> 5, d = lc & 31;
                float val = acc[i][j][r];
                size_t qidx = (((size_t)ss*HEADS + h)*RDIM + rr)*DH + d;
                if (seg == 0)      qo[qidx] = f2bf(val * 0.17677669529663687f);
                else if (seg == 1) ko[qidx] = f2bf(val);
                else if (seg == 2) vo[qidx] = f2bf(val);
                else {
                    float x = val + bg[lc];
                    go[(size_t)m*CS + lc] = f2bf(1.f / (1.f + expf(-x)));
                }
            }
        }
    }
}

// ---- attention: swapped-QK^T MFMA flash, block per (s,h), 4 waves -------
// pb staged via async global_load_lds (both-sides XOR chunk swizzle).
// P/O bf16 packing via v_cvt_pk_bf16_f32 (1 op per pair vs ~10 manual).
__global__ __launch_bounds__(256, 2) void attn_kernel(
        const unsigned short* __restrict__ q, const unsigned short* __restrict__ k,
        const unsigned short* __restrict__ v, const unsigned short* __restrict__ pb,
        const float* __restrict__ mask, unsigned short* __restrict__ o) {
    __shared__ alignas(16) unsigned short Klds[256][40];
    __shared__ alignas(16) unsigned short Vtlds[32][264];
    __shared__ alignas(16) unsigned short PBpb[4][4096];   // per-wave pb tile (swizzled)
    __shared__ alignas(16) unsigned short Plds[4][16][72]; // P / O bounce
    __shared__ float masklds[256];

    const int sh = blockIdx.x;                   // s*8 + h
    const int ss = sh >> 3, h = sh & 7;
    const int tid = threadIdx.x;
    const int lane = tid & 63, wid = tid >> 6;
    const int ln15 = lane & 15, g = lane >> 4;   // g in 0..3

    const unsigned short* kp = k + (size_t)sh * 8192;
    const unsigned short* vp = v + (size_t)sh * 8192;
    const unsigned short* pbh = pb + (size_t)h * ZROWS;
    unsigned short* pbw = &PBpb[wid][0];

    // ---- async-stage pb tile qt=0 (before K/V staging: long cover) ------
    {
        const unsigned short* pbase = pbh + (size_t)(wid*64) * RDIM;
        #pragma unroll
        for (int j = 0; j < 8; j++) {
            int w = j*64 + lane;
            int n = w ^ ((w >> 5) & 7);          // involution chunk swizzle
            const unsigned short* src = pbase + (n >> 5) * RDIM + (n & 31) * 8;
            __builtin_amdgcn_global_load_lds(
                (const __attribute__((address_space(1))) unsigned int*)src,
                (__attribute__((address_space(3))) unsigned int*)(pbw + j*512),
                16, 0, 0);
        }
    }

    // ---- stage K and V^T to LDS ----
    #pragma unroll
    for (int i = 0; i < 4; i++) {
        int idx = tid + i*256;                   // chunk of 8 bf16, 0..1023
        int row = idx >> 2, col = (idx & 3) * 8; // row: k-index, col: d
        short8_t kv8 = *(const short8_t*)&kp[(size_t)row*DH + col];
        short8_t vv8 = *(const short8_t*)&vp[(size_t)row*DH + col];
        *(short8_t*)&Klds[row][col] = kv8;
        #pragma unroll
        for (int e = 0; e < 8; e++)
            Vtlds[col+e][row] = (unsigned short)vv8[e];
    }
    masklds[tid] = 1e9f * (mask[(size_t)ss*RDIM + tid] - 1.f);

    // ---- Q B-frags for the wave's 4 q-tiles (col=ln15=q, k=g*8 over d) --
    short8_t qfr[4];
    {
        const unsigned short* qp = q + (size_t)sh * 8192;
        #pragma unroll
        for (int qt = 0; qt < 4; qt++)
            qfr[qt] = *(const short8_t*)&qp[(size_t)(wid*64 + qt*16 + ln15)*DH + g*8];
    }
    __syncthreads();

    #pragma unroll 1
    for (int qt = 0; qt < 4; qt++) {
        const int q0 = wid*64 + qt*16;
        // ---- S^T = K . Q^T (LDS deps only; pb gll still in flight) ------
        f32x4 st[16];
        #pragma unroll
        for (int t = 0; t < 16; t++) {
            short8_t kf = *(const short8_t*)&Klds[t*16 + ln15][g*8];
            st[t] = __builtin_amdgcn_mfma_f32_16x16x32_bf16(
                        kf, qfr[qt], (f32x4){0.f,0.f,0.f,0.f}, 0, 0, 0);
        }
        // ---- pb landed? then bias: pb (swizzled LDS) + mask (bcast) -----
        asm volatile("s_waitcnt vmcnt(0)" ::: "memory");
        __builtin_amdgcn_sched_barrier(0);
        #pragma unroll
        for (int t = 0; t < 16; t++) {
            int n = ln15*32 + t*2 + (g >> 1);
            int m = n ^ (ln15 & 7);
            uint2 p2 = *(const uint2*)&pbw[m*8 + (g & 1)*4];
            float4 mk4 = *(const float4*)&masklds[t*16 + g*4];
            st[t][0] += bf2f((unsigned short)(p2.x & 0xffffu)) + mk4.x;
            st[t][1] += bf2f((unsigned short)(p2.x >> 16))     + mk4.y;
            st[t][2] += bf2f((unsigned short)(p2.y & 0xffffu)) + mk4.z;
            st[t][3] += bf2f((unsigned short)(p2.y >> 16))     + mk4.w;
        }
        // ---- single-pass softmax, in-lane + 2 shuffles across g ---------
        float mx = -INFINITY;
        #pragma unroll
        for (int t = 0; t < 16; t++) {
            float a = fmaxf(fmaxf(st[t][0], st[t][1]), fmaxf(st[t][2], st[t][3]));
            mx = fmaxf(mx, a);
        }
        mx = fmaxf(mx, __shfl_xor(mx, 16, 64));
        mx = fmaxf(mx, __shfl_xor(mx, 32, 64));
        const float mxl = mx * LOG2E;
        float l = 0.f;
        #pragma unroll
        for (int t = 0; t < 16; t++) {
            #pragma unroll
            for (int r = 0; r < 4; r++) {
                float p = exp2f(fmaf(st[t][r], LOG2E, -mxl));
                st[t][r] = p;
                l += p;
            }
        }
        l += __shfl_xor(l, 16, 64);
        l += __shfl_xor(l, 32, 64);
        float inv = 1.f / l;
        // ---- issue next tile's pb gll (buffer free; covers under PV) ----
        if (qt < 3) {
            const unsigned short* pbase = pbh + (size_t)(q0 + 16) * RDIM;
            #pragma unroll
            for (int j = 0; j < 8; j++) {
                int w = j*64 + lane;
                int n = w ^ ((w >> 5) & 7);
                const unsigned short* src = pbase + (n >> 5) * RDIM + (n & 31) * 8;
                __builtin_amdgcn_global_load_lds(
                    (const __attribute__((address_space(1))) unsigned int*)src,
                    (__attribute__((address_space(3))) unsigned int*)(pbw + j*512),
                    16, 0, 0);
            }
        }
        // ---- PV per 64-k chunk: P -> Plds (cvt_pk), O^T += V^T . P^T ----
        f32x4 oacc[2];
        oacc[0] = (f32x4){0.f,0.f,0.f,0.f};
        oacc[1] = (f32x4){0.f,0.f,0.f,0.f};
        #pragma unroll
        for (int c = 0; c < 4; c++) {
            #pragma unroll
            for (int tc = 0; tc < 4; tc++) {
                int t = c*4 + tc;
                uint2 w;
                w.x = cvt_pk_bf16(st[t][0], st[t][1]);
                w.y = cvt_pk_bf16(st[t][2], st[t][3]);
                *(uint2*)&Plds[wid][ln15][tc*16 + g*4] = w;
            }
            #pragma unroll
            for (int ks = 0; ks < 2; ks++) {
                short8_t pfr = *(const short8_t*)&Plds[wid][ln15][ks*32 + g*8];
                #pragma unroll
                for (int dt = 0; dt < 2; dt++) {
                    short8_t vf = *(const short8_t*)&Vtlds[dt*16 + ln15][c*64 + ks*32 + g*8];
                    oacc[dt] = __builtin_amdgcn_mfma_f32_16x16x32_bf16(
                                   vf, pfr, oacc[dt], 0, 0, 0);
                }
            }
        }
        // ---- epilogue: O^T -> Plds [q][d] -> coalesced 16B stores -------
        #pragma unroll
        for (int dt = 0; dt < 2; dt++) {
            uint2 w;
            w.x = cvt_pk_bf16(oacc[dt][0]*inv, oacc[dt][1]*inv);
            w.y = cvt_pk_bf16(oacc[dt][2]*inv, oacc[dt][3]*inv);
            *(uint2*)&Plds[wid][ln15][dt*16 + g*4] = w;
        }
        {
            int qr = lane >> 2, dc = (lane & 3) * 8;
            short8_t ov = *(const short8_t*)&Plds[wid][qr][dc];
            *(short8_t*)&o[((size_t)ss*RDIM + q0 + qr)*CS + h*DH + dc] = ov;
        }
    }
}

// ------------- output projection (MFMA): out = (o .* g) @ wo + bo --------
__global__ __launch_bounds__(256, 2) void outproj_kernel(
        const unsigned short* __restrict__ ob, const unsigned short* __restrict__ gb,
        const unsigned short* __restrict__ wot, const float* __restrict__ bo,
        float* __restrict__ out) {
    __shared__ alignas(16) unsigned short As[128][72];
    __shared__ alignas(16) unsigned short Bs[128][72];
    const int bx = blockIdx.x;
    const int mblk = (bx & 7) * 32 + (bx >> 3);  // XCD-contiguous m-chunks
    const int m0 = mblk * 128;
    const int n0 = blockIdx.y * 128;             // 0 or 128
    const int tid = threadIdx.x;
    const int lane = tid & 63, wid = tid >> 6;
    const int ln15 = lane & 15, g = lane >> 4;
    const int wr = wid >> 1, wc = wid & 1;
    f32x4 acc[4][4];
    #pragma unroll
    for (int i = 0; i < 4; i++)
        #pragma unroll
        for (int j = 0; j < 4; j++) acc[i][j] = (f32x4){0.f,0.f,0.f,0.f};

    for (int k0 = 0; k0 < 256; k0 += 64) {
        #pragma unroll
        for (int c = 0; c < 4; c++) {
            int L = tid + c*256;
            int row = L >> 3, kc = (L & 7) * 8;
            short8_t ov = *(const short8_t*)&ob[(size_t)(m0+row)*256 + k0 + kc];
            short8_t gv = *(const short8_t*)&gb[(size_t)(m0+row)*256 + k0 + kc];
            unsigned pr[4];
            #pragma unroll
            for (int e = 0; e < 4; e++) {
                float p0 = bf2f((unsigned short)ov[e*2+0]) * bf2f((unsigned short)gv[e*2+0]);
                float p1 = bf2f((unsigned short)ov[e*2+1]) * bf2f((unsigned short)gv[e*2+1]);
                pr[e] = cvt_pk_bf16(p0, p1);
            }
            *(uint4*)&As[row][kc] = *(uint4*)pr;
            *(short8_t*)&Bs[row][kc] =
                *(const short8_t*)&wot[(size_t)(n0+row)*256 + k0 + kc];
        }
        __syncthreads();
        #pragma unroll
        for (int kk = 0; kk < 64; kk += 32) {
            short8_t a[4], b[4];
            #pragma unroll
            for (int i = 0; i < 4; i++) {
                a[i] = *(const short8_t*)&As[wr*64 + i*16 + ln15][kk + g*8];
                b[i] = *(const short8_t*)&Bs[wc*64 + i*16 + ln15][kk + g*8];
            }
            #pragma unroll
            for (int i = 0; i < 4; i++)
                #pragma unroll
                for (int j = 0; j < 4; j++)
                    acc[i][j] = __builtin_amdgcn_mfma_f32_16x16x32_bf16(
                                    a[i], b[j], acc[i][j], 0, 0, 0);
        }
        __syncthreads();
    }
    #pragma unroll
    for (int i = 0; i < 4; i++) {
        #pragma unroll
        for (int r = 0; r < 4; r++) {
            int m = m0 + wr*64 + i*16 + g*4 + r;
            #pragma unroll
            for (int j = 0; j < 4; j++) {
                int col = n0 + wc*64 + j*16 + ln15;
                out[(size_t)m*CS + col] = acc[i][j][r] + bo[col];
            }
        }
    }
}

extern "C" void kernel_launch(void* const* d_in, const int* in_sizes, int n_in,
                              void* d_out, int out_size, void* d_ws, size_t ws_size,
                              hipStream_t stream) {
    const float* s      = (const float*)d_in[0];
    const float* z      = (const float*)d_in[1];
    const float* mask   = (const float*)d_in[2];
    const float* ln_s_w = (const float*)d_in[3];
    const float* ln_s_b = (const float*)d_in[4];
    const float* ln_z_w = (const float*)d_in[5];
    const float* ln_z_b = (const float*)d_in[6];
    const float* w_z    = (const float*)d_in[7];
    const float* w_q    = (const float*)d_in[8];
    const float* w_k    = (const float*)d_in[9];
    const float* w_v    = (const float*)d_in[10];
    const float* w_g    = (const float*)d_in[11];
    const float* b_g    = (const float*)d_in[12];
    const float* w_o    = (const float*)d_in[13];
    const float* b_o    = (const float*)d_in[14];
    float* out = (float*)d_out;
    float* ws  = (float*)d_ws;

    // Workspace layout (float units; bf16 buffers cast):
    unsigned short* snb = (unsigned short*)ws;                    // 8388608 shorts
    unsigned short* wtb = (unsigned short*)(ws + 4194304);        // 262144 shorts
    unsigned short* wot = (unsigned short*)(ws + 4194304+131072); // 65536 shorts
    unsigned short* pbb = (unsigned short*)(ws + 4194304+131072+32768); // 524288 shorts (bf16)
    float* after_pb = ws + 4194304 + 131072 + 32768 + 262144;
    unsigned short* qb  = (unsigned short*)after_pb;              // 8388608 shorts each
    unsigned short* kb  = qb + 8388608;
    unsigned short* vb  = kb + 8388608;
    unsigned short* gbuf= vb + 8388608;
    unsigned short* obuf= gbuf + 8388608;

    ln_s_kernel<<<MROWS/4, 256, 0, stream>>>(s, ln_s_w, ln_s_b, snb);
    ln_z_pb_kernel<<<ZROWS/4, 256, 0, stream>>>(z, ln_z_w, ln_z_b, w_z, pbb);
    wconv_kernel<<<dim3(4,4,5), 256, 0, stream>>>(w_q, w_k, w_v, w_g, w_o, wtb, wot);
    qkvg_kernel<<<dim3(MROWS/128, 8), 256, 0, stream>>>(snb, wtb, b_g, qb, kb, vb, gbuf);
    attn_kernel<<<SDIM*HEADS, 256, 0, stream>>>(qb, kb, vb, pbb, mask, obuf);
    outproj_kernel<<<dim3(MROWS/128, 2), 256, 0, stream>>>(obuf, gbuf, wot, b_o, out);
}